// Round 4
// baseline (2868.270 us; speedup 1.0000x reference)
//
#include <hip/hip_runtime.h>
#include <hip/hip_bf16.h>
#include <math.h>

#define N_NODES 50000
#define N_EDGES 640000
#define HID 128
#define NFILT 128
#define NG 50
#define NGPAD 64
#define NL 3
#define NGRAPHS 64

typedef __attribute__((ext_vector_type(8))) short bf16x8;
typedef __attribute__((ext_vector_type(4))) float f32x4;

// ---------------- module-scope device buffers (no d_ws dependence) ----------
__device__ __align__(16) float g_h  [N_NODES * HID];   // node features (f32)
__device__ __align__(16) float g_xf [N_NODES * HID];   // xf / conv2-out scratch
__device__ __align__(16) float g_agg[N_NODES * HID];   // edge-aggregation target
__device__ __align__(16) float g_d  [N_EDGES];         // per-edge distance
__device__ __align__(16) float g_C  [N_EDGES];         // per-edge cosine cutoff
__device__ __align__(16) float g_gout[NGRAPHS];        // per-graph energy accum

__device__ __forceinline__ float* selbuf(int w){
    return (w == 0) ? g_h : (w == 1) ? g_xf : g_agg;
}

__device__ __forceinline__ unsigned short f2bfbits(float x){
    __hip_bfloat16 b = __float2bfloat16(x);
    union { __hip_bfloat16 b; unsigned short u; } v; v.b = b; return v.u;
}
// ShiftedSoftplus: softplus(x) - ln2, overflow-safe
__device__ __forceinline__ float sspf(float x){
    return fmaxf(x, 0.0f) + log1pf(__expf(-fabsf(x))) - 0.69314718055994530942f;
}

// ---------------- zero the aggregation buffer + graph accumulator ------------
__global__ __launch_bounds__(256) void zero_kernel(){
    int i = blockIdx.x * 256 + threadIdx.x;          // 6250*256 = 1.6e6 float4s exactly
    if (i * 4 < N_NODES * HID)
        *(float4*)&g_agg[i * 4] = make_float4(0.f, 0.f, 0.f, 0.f);
    if (blockIdx.x == 0 && threadIdx.x < NGRAPHS) g_gout[threadIdx.x] = 0.0f;
}

// ---------------- geometry: per-edge d and cosine cutoff C -------------------
__global__ __launch_bounds__(256) void geom_kernel(
    const float* __restrict__ pos,
    const int* __restrict__ src, const int* __restrict__ dst)
{
    int e = blockIdx.x * 256 + threadIdx.x;
    if (e >= N_EDGES) return;
    int s = src[e], t = dst[e];
    float dx = pos[3*t]   - pos[3*s];
    float dy = pos[3*t+1] - pos[3*s+1];
    float dz = pos[3*t+2] - pos[3*s+2];
    float d = sqrtf(dx*dx + dy*dy + dz*dz);
    g_d[e] = d;
    g_C[e] = 0.5f * (__cosf(d * 0.62831853071795864769f) + 1.0f);  // pi/cutoff
}

// ---------------- h init: embedding gather ----------------------------------
__global__ __launch_bounds__(256) void hinit_kernel(
    const int* __restrict__ z, const float* __restrict__ emb)
{
    int idx = blockIdx.x * 256 + threadIdx.x;
    if (idx >= N_NODES * HID) return;
    int n = idx >> 7, f = idx & 127;
    g_h[idx] = emb[z[n] * HID + f];
}

// ---------------- node linear, K split in halves of 64 ----------------------
// mode 0: out = acc (+bias)   mode 1: out += acc (+bias)   mode 2: out = ssp(out+acc)
__global__ __launch_bounds__(256) void node_half_kernel(
    int in_sel, const float* __restrict__ W,
    const float* __restrict__ bias, int out_sel,
    int k0, int mode)
{
    const float* in = selbuf(in_sel);
    float* out = selbuf(out_sel);
    __shared__ __align__(16) float ws[64 * NFILT];   // 32 KB f32 weights rows k0..k0+63
    __shared__ __align__(16) float hs[8][64];        // 2 KB
    __shared__ __align__(16) float bs[NFILT];
    int tid = threadIdx.x;
    for (int i = tid; i < 64 * NFILT; i += 256) ws[i] = W[i];
    if (tid < NFILT) bs[tid] = bias ? bias[tid] : 0.0f;
    __syncthreads();
    int nsub = tid >> 5, jb = (tid & 31) * 4;
    for (int base = blockIdx.x * 8; base < N_NODES; base += gridDim.x * 8){
        for (int i = tid; i < 8 * 64; i += 256){
            int nn = i >> 6, k = i & 63;
            hs[nn][k] = in[(size_t)(base + nn) * HID + k0 + k];
        }
        __syncthreads();
        float4 acc = *(const float4*)&bs[jb];
        #pragma unroll 8
        for (int k = 0; k < 64; k++){
            float a = hs[nsub][k];
            float4 w = *(const float4*)&ws[k * NFILT + jb];
            acc.x = fmaf(a, w.x, acc.x); acc.y = fmaf(a, w.y, acc.y);
            acc.z = fmaf(a, w.z, acc.z); acc.w = fmaf(a, w.w, acc.w);
        }
        size_t o = (size_t)(base + nsub) * NFILT + jb;
        if (mode == 0){ *(float4*)&out[o] = acc; }
        else if (mode == 1){
            out[o+0] += acc.x; out[o+1] += acc.y; out[o+2] += acc.z; out[o+3] += acc.w;
        } else {
            out[o+0] = sspf(out[o+0] + acc.x); out[o+1] = sspf(out[o+1] + acc.y);
            out[o+2] = sspf(out[o+2] + acc.z); out[o+3] = sspf(out[o+3] + acc.w);
        }
        __syncthreads();
    }
}

// ---------------- fused edge-filter MLP (MFMA) + gather/modulate/scatter ----
__global__ __launch_bounds__(256) void edge_kernel(
    const int* __restrict__ src, const int* __restrict__ dst,
    const float* __restrict__ w1g, const float* __restrict__ b1g,
    const float* __restrict__ w2g, const float* __restrict__ b2g)
{
    __shared__ __align__(16) unsigned short w1T[NFILT * NGPAD];  // [n][k] 16 KB bf16
    __shared__ __align__(16) unsigned short w2T[NFILT * NFILT];  // [n][k] 32 KB bf16
    __shared__ __align__(16) unsigned short ea_s[32][NGPAD];     // 4 KB A of GEMM1
    __shared__ __align__(16) unsigned short t_s[32 * NFILT];     // 8 KB A of GEMM2
    __shared__ __align__(16) float b1s[NFILT];
    __shared__ __align__(16) float b2s[NFILT];
    __shared__ __align__(16) float cvals[32];
    __shared__ __align__(16) float dl[32];
    __shared__ __align__(16) int sidx[32];
    __shared__ __align__(16) int didx[32];
    int tid = threadIdx.x;
    for (int i = tid; i < NFILT * NGPAD; i += 256){
        int n = i >> 6, k = i & 63;
        w1T[i] = (k < NG) ? f2bfbits(w1g[k * NFILT + n]) : (unsigned short)0;
    }
    for (int i = tid; i < NFILT * NFILT; i += 256){
        int n = i >> 7, k = i & 127;
        w2T[i] = f2bfbits(w2g[k * NFILT + n]);
    }
    if (tid < NFILT){ b1s[tid] = b1g[tid]; b2s[tid] = b2g[tid]; }
    __syncthreads();

    int wave = tid >> 6, lane = tid & 63, quad = lane >> 4, l16 = lane & 15;
    int mtile = (wave & 1) * 16;          // which 16-edge row tile
    int nbase = (wave >> 1) * 64;         // which 64-col half

    const float STEP = 5.0f / 49.0f;
    const float COEF = -0.5f / (STEP * STEP);

    for (int base = blockIdx.x * 32; base < N_EDGES; base += gridDim.x * 32){
        if (tid < 32){
            int e = base + tid;
            sidx[tid]  = src[e];
            didx[tid]  = dst[e];
            cvals[tid] = g_C[e];
            dl[tid]    = g_d[e];
        }
        __syncthreads();
        {   // on-the-fly gaussian * envelope -> bf16 A tile (32x64), 8 vals/thread
            int el = tid >> 3, seg = tid & 7;
            float d = dl[el];
            float srel = d * 0.2f;
            float den = 1.0f - srel * srel;
            float env = (srel < 1.0f) ? __expf(1.0f - 1.0f / den) : 0.0f;
            unsigned int w[4];
            #pragma unroll
            for (int p = 0; p < 4; p++){
                int g0 = seg * 8 + p * 2, g1 = g0 + 1;
                float dd0 = d - STEP * (float)g0;
                float dd1 = d - STEP * (float)g1;
                float v0 = (g0 < NG) ? __expf(COEF * dd0 * dd0) * env : 0.0f;
                float v1 = (g1 < NG) ? __expf(COEF * dd1 * dd1) * env : 0.0f;
                w[p] = (unsigned int)f2bfbits(v0) | ((unsigned int)f2bfbits(v1) << 16);
            }
            uint4 q; q.x = w[0]; q.y = w[1]; q.z = w[2]; q.w = w[3];
            *(uint4*)&ea_s[el][seg * 8] = q;
        }
        __syncthreads();

        // ---- GEMM1: t = ssp(eattr @ w1 + b1)  [32,64]x[64,128]
        bf16x8 a0 = *(const bf16x8*)&ea_s[mtile + l16][quad * 8];
        bf16x8 a1 = *(const bf16x8*)&ea_s[mtile + l16][32 + quad * 8];
        f32x4 acc[4] = {};
        #pragma unroll
        for (int nt = 0; nt < 4; nt++){
            int n = nbase + nt * 16 + l16;
            bf16x8 b0 = *(const bf16x8*)&w1T[n * NGPAD + quad * 8];
            bf16x8 b1 = *(const bf16x8*)&w1T[n * NGPAD + 32 + quad * 8];
            acc[nt] = __builtin_amdgcn_mfma_f32_16x16x32_bf16(a0, b0, acc[nt], 0, 0, 0);
            acc[nt] = __builtin_amdgcn_mfma_f32_16x16x32_bf16(a1, b1, acc[nt], 0, 0, 0);
        }
        #pragma unroll
        for (int nt = 0; nt < 4; nt++){
            int n = nbase + nt * 16 + l16;
            float bb = b1s[n];
            #pragma unroll
            for (int r = 0; r < 4; r++){
                float v = sspf(acc[nt][r] + bb);
                t_s[(mtile + quad * 4 + r) * NFILT + n] = f2bfbits(v);  // C/D -> A layout
            }
        }
        __syncthreads();

        // ---- GEMM2: W = t @ w2 + b2, then *C, gather xf[src], scatter agg[dst]
        bf16x8 av[4];
        #pragma unroll
        for (int ks = 0; ks < 4; ks++)
            av[ks] = *(const bf16x8*)&t_s[(mtile + l16) * NFILT + ks * 32 + quad * 8];
        f32x4 acc2[4] = {};
        #pragma unroll
        for (int nt = 0; nt < 4; nt++){
            int n = nbase + nt * 16 + l16;
            #pragma unroll
            for (int ks = 0; ks < 4; ks++){
                bf16x8 bv = *(const bf16x8*)&w2T[n * NFILT + ks * 32 + quad * 8];
                acc2[nt] = __builtin_amdgcn_mfma_f32_16x16x32_bf16(av[ks], bv, acc2[nt], 0, 0, 0);
            }
        }
        #pragma unroll
        for (int nt = 0; nt < 4; nt++){
            int n = nbase + nt * 16 + l16;
            float bb = b2s[n];
            #pragma unroll
            for (int r = 0; r < 4; r++){
                int el = mtile + quad * 4 + r;
                float Wv = (acc2[nt][r] + bb) * cvals[el];
                float xv = g_xf[(size_t)sidx[el] * HID + n];
                __hip_atomic_fetch_add(&g_agg[(size_t)didx[el] * HID + n], Wv * xv,
                                       __ATOMIC_RELAXED, __HIP_MEMORY_SCOPE_AGENT);
            }
        }
        __syncthreads();
    }
}

// ---------------- output head: ssp(h@W1+b1)@W2+b2 -> graph segment sum ------
__global__ __launch_bounds__(256) void head_kernel(
    const float* __restrict__ w1g, const float* __restrict__ b1g,
    const float* __restrict__ w2g, const float* __restrict__ b2g,
    const int* __restrict__ batch)
{
    __shared__ __align__(16) float w1h[HID * 64];   // 32 KB
    __shared__ __align__(16) float w2h[64];
    __shared__ __align__(16) float b1h[64];
    __shared__ __align__(16) float hrow[4][HID];
    __shared__ float sb2;
    int tid = threadIdx.x;
    for (int i = tid; i < HID * 64; i += 256) w1h[i] = w1g[i];
    if (tid < 64){ w2h[tid] = w2g[tid]; b1h[tid] = b1g[tid]; }
    if (tid == 0) sb2 = b2g[0];
    int wave = tid >> 6, lane = tid & 63;
    int node = blockIdx.x * 4 + wave;
    if (node < N_NODES){
        hrow[wave][lane]      = g_h[(size_t)node * HID + lane];
        hrow[wave][64 + lane] = g_h[(size_t)node * HID + 64 + lane];
    }
    __syncthreads();
    if (node < N_NODES){
        float acc = b1h[lane];
        #pragma unroll 8
        for (int k = 0; k < HID; k++) acc = fmaf(hrow[wave][k], w1h[k * 64 + lane], acc);
        acc = sspf(acc) * w2h[lane];
        for (int off = 32; off > 0; off >>= 1) acc += __shfl_down(acc, off, 64);
        if (lane == 0)
            __hip_atomic_fetch_add(&g_gout[batch[node]], acc + sb2,
                                   __ATOMIC_RELAXED, __HIP_MEMORY_SCOPE_AGENT);
    }
}

__global__ void store_kernel(float* __restrict__ out){
    int i = threadIdx.x;
    if (i < NGRAPHS) out[i] = g_gout[i];
}

extern "C" void kernel_launch(void* const* d_in, const int* in_sizes, int n_in,
                              void* d_out, int out_size, void* d_ws, size_t ws_size,
                              hipStream_t stream)
{
    const int* z       = (const int*)d_in[0];
    const float* pos   = (const float*)d_in[1];
    const int* ei      = (const int*)d_in[2];
    const int* src = ei;
    const int* dst = ei + N_EDGES;
    const int* batch   = (const int*)d_in[3];
    const float* emb     = (const float*)d_in[4];
    const float* mlp_w1  = (const float*)d_in[5];
    const float* mlp_b1  = (const float*)d_in[6];
    const float* mlp_w2  = (const float*)d_in[7];
    const float* mlp_b2  = (const float*)d_in[8];
    const float* conv1_w = (const float*)d_in[9];
    const float* conv2_w = (const float*)d_in[10];
    const float* conv2_b = (const float*)d_in[11];
    const float* lin_w   = (const float*)d_in[12];
    const float* lin_b   = (const float*)d_in[13];
    const float* out1_w  = (const float*)d_in[14];
    const float* out1_b  = (const float*)d_in[15];
    const float* out2_w  = (const float*)d_in[16];
    const float* out2_b  = (const float*)d_in[17];
    (void)d_ws; (void)ws_size; (void)in_sizes; (void)n_in; (void)out_size;

    geom_kernel<<<(N_EDGES + 255) / 256, 256, 0, stream>>>(pos, src, dst);
    hinit_kernel<<<(N_NODES * HID + 255) / 256, 256, 0, stream>>>(z, emb);

    for (int l = 0; l < NL; l++){
        const float* c1 = conv1_w + (size_t)l * HID * NFILT;
        // xf = h @ conv1_w (no bias)
        node_half_kernel<<<512, 256, 0, stream>>>(0, c1,              nullptr, 1, 0, 0);
        node_half_kernel<<<512, 256, 0, stream>>>(0, c1 + 64 * NFILT, nullptr, 1, 64, 1);
        zero_kernel<<<N_NODES * HID / 4 / 256, 256, 0, stream>>>();
        edge_kernel<<<512, 256, 0, stream>>>(src, dst,
            mlp_w1 + (size_t)l * NG * NFILT, mlp_b1 + (size_t)l * NFILT,
            mlp_w2 + (size_t)l * NFILT * NFILT, mlp_b2 + (size_t)l * NFILT);
        // xf <- ssp(agg @ conv2_w + b)   (old xf dead after edge_kernel)
        const float* c2 = conv2_w + (size_t)l * NFILT * HID;
        node_half_kernel<<<512, 256, 0, stream>>>(2, c2,            conv2_b + (size_t)l * HID, 1, 0, 0);
        node_half_kernel<<<512, 256, 0, stream>>>(2, c2 + 64 * HID, nullptr,                   1, 64, 2);
        // h += xf @ lin_w + lin_b
        const float* lw = lin_w + (size_t)l * HID * HID;
        node_half_kernel<<<512, 256, 0, stream>>>(1, lw,            lin_b + (size_t)l * HID,   0, 0, 1);
        node_half_kernel<<<512, 256, 0, stream>>>(1, lw + 64 * HID, nullptr,                   0, 64, 1);
    }

    head_kernel<<<(N_NODES + 3) / 4, 256, 0, stream>>>(out1_w, out1_b, out2_w, out2_b, batch);
    store_kernel<<<1, 64, 0, stream>>>((float*)d_out);
}

// Round 5
// 1351.843 us; speedup vs baseline: 2.1217x; 2.1217x over previous
//
#include <hip/hip_runtime.h>
#include <math.h>

#define N_NODES 50000
#define N_EDGES 640000
#define HID 128
#define NL 3
#define NGRAPHS 64
#define NT 2048
#define DMAX 1.7330f
#define NPAD 50176   // 196*256

// ---------------- module-scope device buffers -------------------------------
__device__ __align__(16) float g_h  [N_NODES * HID];
__device__ __align__(16) float g_xf [N_NODES * HID];
__device__ __align__(16) float g_agg[N_NODES * HID];
__device__ __align__(16) float g_table[NL * NT * HID];   // W(d)*C(d) per layer
__device__ __align__(16) int   g_cnt[NPAD];
__device__ __align__(16) int   g_ex [NPAD];
__device__ __align__(16) int   g_row[NPAD];
__device__ __align__(16) int   g_part[256];
__device__ __align__(16) int   g_ssrc[N_EDGES];
__device__ __align__(16) int   g_sdst[N_EDGES];
__device__ __align__(16) float g_sx  [N_EDGES];          // d * INVH (table coord)
__device__ __align__(16) float g_gout[NGRAPHS];

__device__ __forceinline__ float* selbuf(int w){
    return (w == 0) ? g_h : (w == 1) ? g_xf : g_agg;
}
__device__ __forceinline__ float sspf(float x){
    return fmaxf(x, 0.0f) + log1pf(__expf(-fabsf(x))) - 0.69314718055994530942f;
}

// ---------------- sorting: counting sort of edges by dst ---------------------
__global__ __launch_bounds__(256) void zero_cnt_kernel(){
    int i = blockIdx.x * 256 + threadIdx.x;
    g_cnt[i] = 0;                                   // NPAD exact
    if (blockIdx.x == 0 && threadIdx.x < NGRAPHS) g_gout[threadIdx.x] = 0.0f;
}
__global__ __launch_bounds__(256) void hist_kernel(const int* __restrict__ dst){
    int e = blockIdx.x * 256 + threadIdx.x;         // 2500*256 exact
    atomicAdd(&g_cnt[dst[e]], 1);
}
__global__ __launch_bounds__(256) void scan1_kernel(){
    __shared__ int s[256];
    int b = blockIdx.x, t = threadIdx.x, i = b * 256 + t;
    int c = g_cnt[i];
    s[t] = c; __syncthreads();
    #pragma unroll
    for (int off = 1; off < 256; off <<= 1){
        int v = (t >= off) ? s[t - off] : 0; __syncthreads();
        s[t] += v; __syncthreads();
    }
    g_ex[i] = s[t] - c;                             // exclusive within block
    if (t == 255) g_part[b] = s[255];
}
__global__ __launch_bounds__(256) void scan2_kernel(){
    __shared__ int s[256];
    int t = threadIdx.x;
    s[t] = (t < 196) ? g_part[t] : 0; __syncthreads();
    #pragma unroll
    for (int off = 1; off < 256; off <<= 1){
        int v = (t >= off) ? s[t - off] : 0; __syncthreads();
        s[t] += v; __syncthreads();
    }
    g_part[t] = s[t];                               // inclusive
}
__global__ __launch_bounds__(256) void scan3_kernel(){
    int b = blockIdx.x, i = b * 256 + threadIdx.x;
    g_row[i] = g_ex[i] + (b > 0 ? g_part[b - 1] : 0);
}
__global__ __launch_bounds__(256) void scatter_kernel(
    const float* __restrict__ pos, const int* __restrict__ src,
    const int* __restrict__ dst)
{
    int e = blockIdx.x * 256 + threadIdx.x;         // exact
    int sv = src[e], dv = dst[e];
    float dx = pos[3*dv]   - pos[3*sv];
    float dy = pos[3*dv+1] - pos[3*sv+1];
    float dz = pos[3*dv+2] - pos[3*sv+2];
    float d = sqrtf(dx*dx + dy*dy + dz*dz);         // < sqrt(3) < DMAX
    int p = atomicAdd(&g_row[dv], 1);
    g_ssrc[p] = sv;
    g_sdst[p] = dv;
    g_sx[p]   = d * ((float)(NT - 1) / DMAX);
}

// ---------------- per-layer filter table: T[i] = W(d_i) * C(d_i) ------------
__global__ __launch_bounds__(128) void table_kernel(
    const float* __restrict__ w1g, const float* __restrict__ b1g,
    const float* __restrict__ w2g, const float* __restrict__ b2g)
{
    int l = blockIdx.x >> 11, pt = blockIdx.x & (NT - 1);
    int n = threadIdx.x;
    float d = pt * (DMAX / (float)(NT - 1));
    __shared__ float ea[64];
    __shared__ float tm[128];
    if (n < 50){
        float srel = d * 0.2f;
        float env = expf(1.0f - 1.0f / (1.0f - srel * srel));
        const float step = 5.0f / 49.0f;
        float dd = d - step * (float)n;
        ea[n] = expf((-0.5f / (step * step)) * dd * dd) * env;
    }
    __syncthreads();
    float acc = b1g[l * 128 + n];
    #pragma unroll 10
    for (int k = 0; k < 50; k++)
        acc = fmaf(ea[k], w1g[(l * 50 + k) * 128 + n], acc);
    tm[n] = sspf(acc);
    __syncthreads();
    float acc2 = b2g[l * 128 + n];
    #pragma unroll 8
    for (int k = 0; k < 128; k++)
        acc2 = fmaf(tm[k], w2g[(l * 128 + k) * 128 + n], acc2);
    float C = 0.5f * (cosf(d * 0.62831853071795864769f) + 1.0f);
    g_table[(l * NT + pt) * 128 + n] = acc2 * C;
}

// ---------------- h init ----------------------------------------------------
__global__ __launch_bounds__(256) void hinit_kernel(
    const int* __restrict__ z, const float* __restrict__ emb)
{
    int idx = blockIdx.x * 256 + threadIdx.x;
    if (idx >= N_NODES * HID) return;
    int n = idx >> 7, f = idx & 127;
    g_h[idx] = emb[z[n] * HID + f];
}

__global__ __launch_bounds__(256) void zero_agg_kernel(){
    int i = blockIdx.x * 256 + threadIdx.x;         // 6250*256 = exact count/4
    *(float4*)&g_agg[i * 4] = make_float4(0.f, 0.f, 0.f, 0.f);
}

// ---------------- node GEMM: 32-node tiles, K-half=64, f32 ------------------
// mode 0: out = acc
// mode 1: out = out + acc + bias
// mode 2: out = ssp(out + acc + bias)
// mode 3: out = out + g_agg + acc + bias   (residual with partial in g_agg)
__global__ __launch_bounds__(256) void node_gemm_kernel(
    int in_sel, const float* __restrict__ W, const float* __restrict__ bias,
    int out_sel, int k0, int mode)
{
    const float* in = selbuf(in_sel);
    float* out = selbuf(out_sel);
    __shared__ __align__(16) float ws[64 * 128];    // 32 KB
    __shared__ __align__(16) float hs[32][68];      // 8.7 KB, 272B rows (16B mult)
    __shared__ __align__(16) float bs[128];
    int tid = threadIdx.x;
    for (int i = tid; i < 64 * 128 / 4; i += 256)
        *(float4*)&ws[i * 4] = *(const float4*)&W[i * 4];
    if (tid < 128) bs[tid] = bias ? bias[tid] : 0.0f;
    int nn0 = tid & 7, jb = ((tid >> 3) & 31) * 4;
    const int NTILES = (N_NODES + 31) / 32;
    for (int t = blockIdx.x; t < NTILES; t += gridDim.x){
        int base = t * 32;
        __syncthreads();
        for (int i = tid; i < 32 * 16; i += 256){   // stage 32 nodes x 64 k (f4)
            int nn = i >> 4, k4 = (i & 15) * 4;
            int node = base + nn;
            float4 v = (node < N_NODES)
                ? *(const float4*)&in[(size_t)node * HID + k0 + k4]
                : make_float4(0.f, 0.f, 0.f, 0.f);
            *(float4*)&hs[nn][k4] = v;
        }
        __syncthreads();
        float4 a0 = {0,0,0,0}, a1 = {0,0,0,0}, a2 = {0,0,0,0}, a3 = {0,0,0,0};
        #pragma unroll 8
        for (int k = 0; k < 64; k++){
            float4 w = *(const float4*)&ws[k * 128 + jb];
            float x0 = hs[nn0][k], x1 = hs[nn0 + 8][k];
            float x2 = hs[nn0 + 16][k], x3 = hs[nn0 + 24][k];
            a0.x = fmaf(x0, w.x, a0.x); a0.y = fmaf(x0, w.y, a0.y);
            a0.z = fmaf(x0, w.z, a0.z); a0.w = fmaf(x0, w.w, a0.w);
            a1.x = fmaf(x1, w.x, a1.x); a1.y = fmaf(x1, w.y, a1.y);
            a1.z = fmaf(x1, w.z, a1.z); a1.w = fmaf(x1, w.w, a1.w);
            a2.x = fmaf(x2, w.x, a2.x); a2.y = fmaf(x2, w.y, a2.y);
            a2.z = fmaf(x2, w.z, a2.z); a2.w = fmaf(x2, w.w, a2.w);
            a3.x = fmaf(x3, w.x, a3.x); a3.y = fmaf(x3, w.y, a3.y);
            a3.z = fmaf(x3, w.z, a3.z); a3.w = fmaf(x3, w.w, a3.w);
        }
        float4 accs[4] = {a0, a1, a2, a3};
        #pragma unroll
        for (int c = 0; c < 4; c++){
            int node = base + nn0 + 8 * c;
            if (node >= N_NODES) continue;
            size_t o = (size_t)node * HID + jb;
            float4 r = accs[c];
            if (mode == 0){
                *(float4*)&out[o] = r;
            } else {
                float4 b4 = *(const float4*)&bs[jb];
                float4 v = *(const float4*)&out[o];
                if (mode == 1){
                    v.x += r.x + b4.x; v.y += r.y + b4.y;
                    v.z += r.z + b4.z; v.w += r.w + b4.w;
                } else if (mode == 2){
                    v.x = sspf(v.x + r.x + b4.x); v.y = sspf(v.y + r.y + b4.y);
                    v.z = sspf(v.z + r.z + b4.z); v.w = sspf(v.w + r.w + b4.w);
                } else {
                    float4 p = *(const float4*)&g_agg[o];
                    v.x += p.x + r.x + b4.x; v.y += p.y + r.y + b4.y;
                    v.z += p.z + r.z + b4.z; v.w += p.w + r.w + b4.w;
                }
                *(float4*)&out[o] = v;
            }
        }
    }
}

// ---------------- fused edge gather/modulate/aggregate (table lookup) -------
__global__ __launch_bounds__(256) void agg_kernel(int l){
    const float* __restrict__ T = g_table + (size_t)l * NT * 128;
    __shared__ int   es[256];
    __shared__ int   ed[256];
    __shared__ float exl[256];
    int tid = threadIdx.x;
    int base = blockIdx.x * 256;                    // 2500 blocks exact
    es[tid]  = g_ssrc[base + tid];
    ed[tid]  = g_sdst[base + tid];
    exl[tid] = g_sx[base + tid];
    __syncthreads();
    int half = tid >> 7, n = tid & 127;
    int j0 = half * 128;
    int cur = ed[j0];
    float acc = 0.0f;
    for (int j = 0; j < 128; j++){
        int el = j0 + j;
        int dv = ed[el];
        if (dv != cur){
            __hip_atomic_fetch_add(&g_agg[(size_t)cur * 128 + n], acc,
                                   __ATOMIC_RELAXED, __HIP_MEMORY_SCOPE_AGENT);
            acc = 0.0f; cur = dv;
        }
        float xe = exl[el];
        int i0 = (int)xe;
        float fr = xe - (float)i0;
        float t0 = T[(size_t)i0 * 128 + n];
        float t1 = T[(size_t)(i0 + 1) * 128 + n];
        float w = fmaf(fr, t1 - t0, t0);
        acc = fmaf(w, g_xf[(size_t)es[el] * 128 + n], acc);
    }
    __hip_atomic_fetch_add(&g_agg[(size_t)cur * 128 + n], acc,
                           __ATOMIC_RELAXED, __HIP_MEMORY_SCOPE_AGENT);
}

// ---------------- output head ----------------------------------------------
__global__ __launch_bounds__(256) void head_kernel(
    const float* __restrict__ w1g, const float* __restrict__ b1g,
    const float* __restrict__ w2g, const float* __restrict__ b2g,
    const int* __restrict__ batch)
{
    __shared__ __align__(16) float w1h[128 * 64];   // 32 KB
    __shared__ __align__(16) float w2h[64];
    __shared__ __align__(16) float b1h[64];
    __shared__ __align__(16) float hrow[4][128];
    int tid = threadIdx.x;
    for (int i = tid; i < 128 * 64 / 4; i += 256)
        *(float4*)&w1h[i * 4] = *(const float4*)&w1g[i * 4];
    if (tid < 64){ w2h[tid] = w2g[tid]; b1h[tid] = b1g[tid]; }
    float sb2 = b2g[0];
    __syncthreads();
    int wave = tid >> 6, lane = tid & 63;
    for (int nb = blockIdx.x * 4; nb < N_NODES; nb += gridDim.x * 4){
        int node = nb + wave;
        __syncthreads();
        if (node < N_NODES){
            hrow[wave][lane]      = g_h[(size_t)node * 128 + lane];
            hrow[wave][64 + lane] = g_h[(size_t)node * 128 + 64 + lane];
        }
        __syncthreads();
        if (node < N_NODES){
            float acc = b1h[lane];
            #pragma unroll 8
            for (int k = 0; k < 128; k++)
                acc = fmaf(hrow[wave][k], w1h[k * 64 + lane], acc);
            acc = sspf(acc) * w2h[lane];
            #pragma unroll
            for (int off = 32; off > 0; off >>= 1) acc += __shfl_down(acc, off, 64);
            if (lane == 0)
                __hip_atomic_fetch_add(&g_gout[batch[node]], acc + sb2,
                                       __ATOMIC_RELAXED, __HIP_MEMORY_SCOPE_AGENT);
        }
    }
}

__global__ void store_kernel(float* __restrict__ out){
    int i = threadIdx.x;
    if (i < NGRAPHS) out[i] = g_gout[i];
}

extern "C" void kernel_launch(void* const* d_in, const int* in_sizes, int n_in,
                              void* d_out, int out_size, void* d_ws, size_t ws_size,
                              hipStream_t stream)
{
    const int* z       = (const int*)d_in[0];
    const float* pos   = (const float*)d_in[1];
    const int* ei      = (const int*)d_in[2];
    const int* src = ei;
    const int* dst = ei + N_EDGES;
    const int* batch   = (const int*)d_in[3];
    const float* emb     = (const float*)d_in[4];
    const float* mlp_w1  = (const float*)d_in[5];
    const float* mlp_b1  = (const float*)d_in[6];
    const float* mlp_w2  = (const float*)d_in[7];
    const float* mlp_b2  = (const float*)d_in[8];
    const float* conv1_w = (const float*)d_in[9];
    const float* conv2_w = (const float*)d_in[10];
    const float* conv2_b = (const float*)d_in[11];
    const float* lin_w   = (const float*)d_in[12];
    const float* lin_b   = (const float*)d_in[13];
    const float* out1_w  = (const float*)d_in[14];
    const float* out1_b  = (const float*)d_in[15];
    const float* out2_w  = (const float*)d_in[16];
    const float* out2_b  = (const float*)d_in[17];
    (void)d_ws; (void)ws_size; (void)in_sizes; (void)n_in; (void)out_size;

    // --- edge sort by dst (once per launch) ---
    zero_cnt_kernel<<<196, 256, 0, stream>>>();
    hist_kernel<<<2500, 256, 0, stream>>>(dst);
    scan1_kernel<<<196, 256, 0, stream>>>();
    scan2_kernel<<<1, 256, 0, stream>>>();
    scan3_kernel<<<196, 256, 0, stream>>>();
    scatter_kernel<<<2500, 256, 0, stream>>>(pos, src, dst);

    // --- per-layer filter tables + h init ---
    table_kernel<<<NL * NT, 128, 0, stream>>>(mlp_w1, mlp_b1, mlp_w2, mlp_b2);
    hinit_kernel<<<(N_NODES * HID + 255) / 256, 256, 0, stream>>>(z, emb);

    for (int l = 0; l < NL; l++){
        const float* c1 = conv1_w + (size_t)l * HID * HID;
        // xf = h @ conv1 (no bias)
        node_gemm_kernel<<<768, 256, 0, stream>>>(0, c1,             nullptr, 1, 0, 0);
        node_gemm_kernel<<<768, 256, 0, stream>>>(0, c1 + 64 * HID,  nullptr, 1, 64, 1);
        zero_agg_kernel<<<6250, 256, 0, stream>>>();
        agg_kernel<<<2500, 256, 0, stream>>>(l);
        // xf = ssp(agg @ conv2 + b)
        const float* c2 = conv2_w + (size_t)l * HID * HID;
        node_gemm_kernel<<<768, 256, 0, stream>>>(2, c2,             nullptr,                 1, 0, 0);
        node_gemm_kernel<<<768, 256, 0, stream>>>(2, c2 + 64 * HID,  conv2_b + (size_t)l*HID, 1, 64, 2);
        // h += xf @ lin + b   (partial of first K-half parked in g_agg)
        const float* lw = lin_w + (size_t)l * HID * HID;
        node_gemm_kernel<<<768, 256, 0, stream>>>(1, lw,             nullptr,                 2, 0, 0);
        node_gemm_kernel<<<768, 256, 0, stream>>>(1, lw + 64 * HID,  lin_b + (size_t)l*HID,   0, 64, 3);
    }

    head_kernel<<<512, 256, 0, stream>>>(out1_w, out1_b, out2_w, out2_b, batch);
    store_kernel<<<1, 64, 0, stream>>>((float*)d_out);
}

// Round 6
// 845.803 us; speedup vs baseline: 3.3912x; 1.5983x over previous
//
#include <hip/hip_runtime.h>
#include <math.h>

#define N_NODES 50000
#define N_EDGES 640000
#define HID 128
#define NL 3
#define NGRAPHS 64
#define NT 2048
#define DMAX 1.7330f
#define NPAD 50176   // 196*256
#define NTILES 1563  // ceil(50000/32)

typedef __attribute__((ext_vector_type(8))) short bf16x8;
typedef __attribute__((ext_vector_type(4))) float f32x4;

// ---------------- module-scope device buffers -------------------------------
__device__ __align__(16) float g_h  [N_NODES * HID];
__device__ __align__(16) float g_xf [N_NODES * HID];
__device__ __align__(16) float g_agg[N_NODES * HID];
__device__ __align__(16) float g_table[NL * NT * HID];    // W(d)*C(d) per layer
__device__ __align__(16) unsigned short g_wT[9 * HID * HID]; // bf16 [n][k] weights
__device__ __align__(16) int   g_cnt[NPAD];
__device__ __align__(16) int   g_ex [NPAD];
__device__ __align__(16) int   g_row[NPAD];
__device__ __align__(16) int   g_part[256];
__device__ __align__(16) int   g_ssrc[N_EDGES];
__device__ __align__(16) int   g_sdst[N_EDGES];
__device__ __align__(16) float g_sx  [N_EDGES];           // d*INVH; later e_atom
__device__ __align__(16) float g_gout[NGRAPHS];

__device__ __forceinline__ float* selbuf(int w){
    return (w == 0) ? g_h : (w == 1) ? g_xf : g_agg;
}
__device__ __forceinline__ unsigned short f2bfbits(float x){
    union { float f; unsigned int i; } v; v.f = x;
    unsigned int lsb = (v.i >> 16) & 1;
    v.i += 0x7fff + lsb;                      // RNE to bf16
    return (unsigned short)(v.i >> 16);
}
__device__ __forceinline__ float sspf(float x){
    return fmaxf(x, 0.0f) + log1pf(__expf(-fabsf(x))) - 0.69314718055994530942f;
}

// ---------------- counting sort of edges by dst ------------------------------
__global__ __launch_bounds__(256) void zero_cnt_kernel(){
    int i = blockIdx.x * 256 + threadIdx.x;
    g_cnt[i] = 0;                                   // NPAD exact
    if (blockIdx.x == 0 && threadIdx.x < NGRAPHS) g_gout[threadIdx.x] = 0.0f;
}
__global__ __launch_bounds__(256) void hist_kernel(const int* __restrict__ dst){
    int e = blockIdx.x * 256 + threadIdx.x;         // 2500*256 exact
    atomicAdd(&g_cnt[dst[e]], 1);
}
__global__ __launch_bounds__(256) void scan1_kernel(){
    __shared__ int s[256];
    int b = blockIdx.x, t = threadIdx.x, i = b * 256 + t;
    int c = g_cnt[i];
    s[t] = c; __syncthreads();
    #pragma unroll
    for (int off = 1; off < 256; off <<= 1){
        int v = (t >= off) ? s[t - off] : 0; __syncthreads();
        s[t] += v; __syncthreads();
    }
    g_ex[i] = s[t] - c;
    if (t == 255) g_part[b] = s[255];
}
__global__ __launch_bounds__(256) void scan2_kernel(){
    __shared__ int s[256];
    int t = threadIdx.x;
    s[t] = (t < 196) ? g_part[t] : 0; __syncthreads();
    #pragma unroll
    for (int off = 1; off < 256; off <<= 1){
        int v = (t >= off) ? s[t - off] : 0; __syncthreads();
        s[t] += v; __syncthreads();
    }
    g_part[t] = s[t];
}
__global__ __launch_bounds__(256) void scan3_kernel(){
    int b = blockIdx.x, i = b * 256 + threadIdx.x;
    g_row[i] = g_ex[i] + (b > 0 ? g_part[b - 1] : 0);
}
__global__ __launch_bounds__(256) void scatter_kernel(
    const float* __restrict__ pos, const int* __restrict__ src,
    const int* __restrict__ dst)
{
    int e = blockIdx.x * 256 + threadIdx.x;         // exact
    int sv = src[e], dv = dst[e];
    float dx = pos[3*dv]   - pos[3*sv];
    float dy = pos[3*dv+1] - pos[3*sv+1];
    float dz = pos[3*dv+2] - pos[3*sv+2];
    float d = sqrtf(dx*dx + dy*dy + dz*dz);         // < sqrt(3) < DMAX
    int p = atomicAdd(&g_row[dv], 1);
    g_ssrc[p] = sv;
    g_sdst[p] = dv;
    g_sx[p]   = d * ((float)(NT - 1) / DMAX);
}

// ---------------- per-layer filter table: T[i] = W(d_i) * C(d_i) ------------
__global__ __launch_bounds__(128) void table_kernel(
    const float* __restrict__ w1g, const float* __restrict__ b1g,
    const float* __restrict__ w2g, const float* __restrict__ b2g)
{
    int l = blockIdx.x >> 11, pt = blockIdx.x & (NT - 1);
    int n = threadIdx.x;
    float d = pt * (DMAX / (float)(NT - 1));
    __shared__ float ea[64];
    __shared__ float tm[128];
    if (n < 50){
        float srel = d * 0.2f;
        float env = expf(1.0f - 1.0f / (1.0f - srel * srel));
        const float step = 5.0f / 49.0f;
        float dd = d - step * (float)n;
        ea[n] = expf((-0.5f / (step * step)) * dd * dd) * env;
    }
    __syncthreads();
    float acc = b1g[l * 128 + n];
    #pragma unroll 10
    for (int k = 0; k < 50; k++)
        acc = fmaf(ea[k], w1g[(l * 50 + k) * 128 + n], acc);
    tm[n] = sspf(acc);
    __syncthreads();
    float acc2 = b2g[l * 128 + n];
    #pragma unroll 8
    for (int k = 0; k < 128; k++)
        acc2 = fmaf(tm[k], w2g[(l * 128 + k) * 128 + n], acc2);
    float C = 0.5f * (cosf(d * 0.62831853071795864769f) + 1.0f);
    g_table[(l * NT + pt) * 128 + n] = acc2 * C;
}

// ---------------- weight prep: bf16 transpose of 9 node matrices ------------
__global__ __launch_bounds__(256) void wprep_kernel(
    const float* __restrict__ c1, const float* __restrict__ c2,
    const float* __restrict__ lw)
{
    int gid = blockIdx.x * 256 + threadIdx.x;       // 576*256 = 147456 exact
    int mat = gid >> 14, r = gid & 16383;
    int n = r & 127, k = r >> 7;
    int l = mat / 3, w = mat % 3;
    const float* base = (w == 0 ? c1 : w == 1 ? c2 : lw) + (size_t)l * HID * HID;
    g_wT[(size_t)mat * HID * HID + n * 128 + k] = f2bfbits(base[k * 128 + n]);
}

// ---------------- h init ----------------------------------------------------
__global__ __launch_bounds__(256) void hinit_kernel(
    const int* __restrict__ z, const float* __restrict__ emb)
{
    int idx = blockIdx.x * 256 + threadIdx.x;
    if (idx >= N_NODES * HID) return;
    int n = idx >> 7, f = idx & 127;
    g_h[idx] = emb[z[n] * HID + f];
}

__global__ __launch_bounds__(256) void zero_agg_kernel(){
    int i = blockIdx.x * 256 + threadIdx.x;         // 6250*256 exact
    *(float4*)&g_agg[i * 4] = make_float4(0.f, 0.f, 0.f, 0.f);
}

// ---------------- node GEMM via MFMA, full K=128 ----------------------------
// mode 0: out = X@W          mode 1: out += X@W + bias    mode 2: out = ssp(X@W + bias)
__global__ __launch_bounds__(256) void node_gemm_kernel(
    int in_sel, int mat, const float* __restrict__ bias, int out_sel, int mode)
{
    const float* in = selbuf(in_sel);
    float* out = selbuf(out_sel);
    __shared__ __align__(16) unsigned short s_w[HID * 128];   // 32 KB bf16 [n][k]
    __shared__ __align__(16) unsigned short a_s[32 * 128];    // 8 KB bf16 nodes
    __shared__ __align__(16) float s_b[128];
    int tid = threadIdx.x;
    const unsigned short* wsrc = g_wT + (size_t)mat * HID * HID;
    for (int i = tid; i < 2048; i += 256){           // swizzled weight stage
        int n = i >> 4, c = i & 15, phys = c ^ (n & 15);
        *(uint4*)&s_w[n * 128 + phys * 8] = *(const uint4*)&wsrc[n * 128 + c * 8];
    }
    if (tid < 128) s_b[tid] = bias ? bias[tid] : 0.0f;

    int wave = tid >> 6, lane = tid & 63, quad = lane >> 4, l16 = lane & 15;
    int mtile = (wave & 1) * 16, nbase = (wave >> 1) * 64;

    for (int t = blockIdx.x; t < NTILES; t += gridDim.x){
        int base = t * 32;
        __syncthreads();                             // a_s free (and s_w ready, 1st iter)
        for (int i = tid; i < 512; i += 256){        // stage 32 nodes x 128 k -> bf16
            int nn = i >> 4, c = i & 15, node = base + nn;
            int phys = c ^ (nn & 15);
            uint4 q = {0u, 0u, 0u, 0u};
            if (node < N_NODES){
                const float* p = &in[(size_t)node * 128 + c * 8];
                float4 f0 = *(const float4*)p;
                float4 f1 = *(const float4*)(p + 4);
                q.x = (unsigned int)f2bfbits(f0.x) | ((unsigned int)f2bfbits(f0.y) << 16);
                q.y = (unsigned int)f2bfbits(f0.z) | ((unsigned int)f2bfbits(f0.w) << 16);
                q.z = (unsigned int)f2bfbits(f1.x) | ((unsigned int)f2bfbits(f1.y) << 16);
                q.w = (unsigned int)f2bfbits(f1.z) | ((unsigned int)f2bfbits(f1.w) << 16);
            }
            *(uint4*)&a_s[nn * 128 + phys * 8] = q;
        }
        __syncthreads();

        bf16x8 av[4];
        int arow = mtile + l16;
        #pragma unroll
        for (int ks = 0; ks < 4; ks++){
            int phys = (ks * 4 + quad) ^ (arow & 15);
            av[ks] = *(const bf16x8*)&a_s[arow * 128 + phys * 8];
        }
        f32x4 acc[4] = {};
        #pragma unroll
        for (int nt = 0; nt < 4; nt++){
            int n = nbase + nt * 16 + l16;
            #pragma unroll
            for (int ks = 0; ks < 4; ks++){
                int phys = (ks * 4 + quad) ^ (n & 15);
                bf16x8 bv = *(const bf16x8*)&s_w[n * 128 + phys * 8];
                acc[nt] = __builtin_amdgcn_mfma_f32_16x16x32_bf16(av[ks], bv, acc[nt], 0, 0, 0);
            }
        }
        #pragma unroll
        for (int nt = 0; nt < 4; nt++){
            int n = nbase + nt * 16 + l16;
            float bb = s_b[n];
            #pragma unroll
            for (int r = 0; r < 4; r++){
                int node = base + mtile + quad * 4 + r;
                if (node >= N_NODES) continue;
                size_t o = (size_t)node * 128 + n;
                float v = acc[nt][r];
                if (mode == 0)      out[o] = v;
                else if (mode == 2) out[o] = sspf(v + bb);
                else                out[o] = out[o] + v + bb;
            }
        }
    }
}

// ---------------- fused edge gather/modulate/aggregate (table lookup) -------
__global__ __launch_bounds__(256) void agg_kernel(int l){
    const float* __restrict__ T = g_table + (size_t)l * NT * 128;
    __shared__ int   es[256];
    __shared__ int   ed[256];
    __shared__ float exl[256];
    int tid = threadIdx.x;
    int base = blockIdx.x * 256;                    // 2500 blocks exact
    es[tid]  = g_ssrc[base + tid];
    ed[tid]  = g_sdst[base + tid];
    exl[tid] = g_sx[base + tid];
    __syncthreads();
    int half = tid >> 7, n = tid & 127;
    int j0 = half * 128;
    int cur = ed[j0];
    float acc = 0.0f;
    for (int j = 0; j < 128; j++){
        int el = j0 + j;
        int dv = ed[el];
        if (dv != cur){
            __hip_atomic_fetch_add(&g_agg[(size_t)cur * 128 + n], acc,
                                   __ATOMIC_RELAXED, __HIP_MEMORY_SCOPE_AGENT);
            acc = 0.0f; cur = dv;
        }
        float xe = exl[el];
        int i0 = (int)xe;
        float fr = xe - (float)i0;
        float t0 = T[(size_t)i0 * 128 + n];
        float t1 = T[(size_t)(i0 + 1) * 128 + n];
        float w = fmaf(fr, t1 - t0, t0);
        acc = fmaf(w, g_xf[(size_t)es[el] * 128 + n], acc);
    }
    __hip_atomic_fetch_add(&g_agg[(size_t)cur * 128 + n], acc,
                           __ATOMIC_RELAXED, __HIP_MEMORY_SCOPE_AGENT);
}

// ---------------- output head: per-node energy (no atomics) -----------------
__global__ __launch_bounds__(256) void head_kernel(
    const float* __restrict__ w1g, const float* __restrict__ b1g,
    const float* __restrict__ w2g, const float* __restrict__ b2g)
{
    __shared__ __align__(16) float w1h[128 * 64];   // 32 KB
    __shared__ __align__(16) float w2h[64];
    __shared__ __align__(16) float b1h[64];
    __shared__ __align__(16) float hrow[4][128];
    int tid = threadIdx.x;
    for (int i = tid; i < 128 * 64 / 4; i += 256)
        *(float4*)&w1h[i * 4] = *(const float4*)&w1g[i * 4];
    if (tid < 64){ w2h[tid] = w2g[tid]; b1h[tid] = b1g[tid]; }
    float sb2 = b2g[0];
    __syncthreads();
    int wave = tid >> 6, lane = tid & 63;
    for (int nb = blockIdx.x * 4; nb < N_NODES; nb += gridDim.x * 4){
        int node = nb + wave;
        __syncthreads();
        if (node < N_NODES){
            hrow[wave][lane]      = g_h[(size_t)node * 128 + lane];
            hrow[wave][64 + lane] = g_h[(size_t)node * 128 + 64 + lane];
        }
        __syncthreads();
        if (node < N_NODES){
            float acc = b1h[lane];
            #pragma unroll 8
            for (int k = 0; k < 128; k++)
                acc = fmaf(hrow[wave][k], w1h[k * 64 + lane], acc);
            acc = sspf(acc) * w2h[lane];
            #pragma unroll
            for (int off = 32; off > 0; off >>= 1) acc += __shfl_down(acc, off, 64);
            if (lane == 0) g_sx[node] = acc + sb2;   // reuse g_sx as e_atom
        }
    }
}

// ---------------- segment-sum of e_atom with LDS pre-reduction --------------
__global__ __launch_bounds__(256) void reduce_kernel(const int* __restrict__ batch){
    __shared__ float part[NGRAPHS];
    int tid = threadIdx.x;
    if (tid < NGRAPHS) part[tid] = 0.0f;
    __syncthreads();
    int i = blockIdx.x * 256 + tid;                 // 196 blocks
    if (i < N_NODES) atomicAdd(&part[batch[i]], g_sx[i]);
    __syncthreads();
    if (tid < NGRAPHS && part[tid] != 0.0f)
        __hip_atomic_fetch_add(&g_gout[tid], part[tid],
                               __ATOMIC_RELAXED, __HIP_MEMORY_SCOPE_AGENT);
}

__global__ void store_kernel(float* __restrict__ out){
    int i = threadIdx.x;
    if (i < NGRAPHS) out[i] = g_gout[i];
}

extern "C" void kernel_launch(void* const* d_in, const int* in_sizes, int n_in,
                              void* d_out, int out_size, void* d_ws, size_t ws_size,
                              hipStream_t stream)
{
    const int* z       = (const int*)d_in[0];
    const float* pos   = (const float*)d_in[1];
    const int* ei      = (const int*)d_in[2];
    const int* src = ei;
    const int* dst = ei + N_EDGES;
    const int* batch   = (const int*)d_in[3];
    const float* emb     = (const float*)d_in[4];
    const float* mlp_w1  = (const float*)d_in[5];
    const float* mlp_b1  = (const float*)d_in[6];
    const float* mlp_w2  = (const float*)d_in[7];
    const float* mlp_b2  = (const float*)d_in[8];
    const float* conv1_w = (const float*)d_in[9];
    const float* conv2_w = (const float*)d_in[10];
    const float* conv2_b = (const float*)d_in[11];
    const float* lin_w   = (const float*)d_in[12];
    const float* lin_b   = (const float*)d_in[13];
    const float* out1_w  = (const float*)d_in[14];
    const float* out1_b  = (const float*)d_in[15];
    const float* out2_w  = (const float*)d_in[16];
    const float* out2_b  = (const float*)d_in[17];
    (void)d_ws; (void)ws_size; (void)in_sizes; (void)n_in; (void)out_size;

    // --- one-time per launch: sort edges by dst, tables, weight prep, h0 ---
    zero_cnt_kernel<<<196, 256, 0, stream>>>();
    hist_kernel<<<2500, 256, 0, stream>>>(dst);
    scan1_kernel<<<196, 256, 0, stream>>>();
    scan2_kernel<<<1, 256, 0, stream>>>();
    scan3_kernel<<<196, 256, 0, stream>>>();
    scatter_kernel<<<2500, 256, 0, stream>>>(pos, src, dst);
    table_kernel<<<NL * NT, 128, 0, stream>>>(mlp_w1, mlp_b1, mlp_w2, mlp_b2);
    wprep_kernel<<<576, 256, 0, stream>>>(conv1_w, conv2_w, lin_w);
    hinit_kernel<<<(N_NODES * HID + 255) / 256, 256, 0, stream>>>(z, emb);

    for (int l = 0; l < NL; l++){
        node_gemm_kernel<<<521, 256, 0, stream>>>(0, l * 3 + 0, nullptr, 1, 0);      // xf = h@c1
        zero_agg_kernel<<<6250, 256, 0, stream>>>();
        agg_kernel<<<2500, 256, 0, stream>>>(l);
        node_gemm_kernel<<<521, 256, 0, stream>>>(2, l * 3 + 1,                      // xf = ssp(agg@c2+b)
                                                  conv2_b + (size_t)l * HID, 1, 2);
        node_gemm_kernel<<<521, 256, 0, stream>>>(1, l * 3 + 2,                      // h += xf@lw+b
                                                  lin_b + (size_t)l * HID, 0, 1);
    }

    head_kernel<<<512, 256, 0, stream>>>(out1_w, out1_b, out2_w, out2_b);
    reduce_kernel<<<196, 256, 0, stream>>>(batch);
    store_kernel<<<1, 64, 0, stream>>>((float*)d_out);
}

// Round 7
// 732.444 us; speedup vs baseline: 3.9160x; 1.1548x over previous
//
#include <hip/hip_runtime.h>
#include <math.h>

#define N_NODES 50000
#define N_EDGES 640000
#define HID 128
#define NL 3
#define NGRAPHS 64
#define NT 2048
#define DMAX 1.7330f
#define NPAD 50176   // 196*256
#define NTILES 1563  // ceil(50000/32)

typedef __attribute__((ext_vector_type(8))) short bf16x8;
typedef __attribute__((ext_vector_type(4))) float f32x4;

// ---------------- module-scope device buffers -------------------------------
__device__ __align__(16) float g_h  [N_NODES * HID];        // f32 node features
__device__ __align__(16) unsigned short g_xfb [N_NODES * HID]; // bf16 xf / xf2
__device__ __align__(16) unsigned short g_aggb[N_NODES * HID]; // bf16 aggregation
__device__ __align__(16) float g_table[NL * NT * HID];      // W(d)*C(d) per layer
__device__ __align__(16) unsigned short g_wT[9 * HID * HID]; // bf16 [n][k] weights
__device__ __align__(16) int   g_cnt[NPAD];
__device__ __align__(16) int   g_ex [NPAD];
__device__ __align__(16) int   g_row[NPAD];
__device__ __align__(16) int   g_part[256];
__device__ __align__(16) int   g_ssrc[N_EDGES];
__device__ __align__(16) float g_sx  [N_EDGES];             // d*INVH; later e_atom
__device__ __align__(16) float g_gout[NGRAPHS];

__device__ __forceinline__ unsigned short f2bfbits(float x){
    union { float f; unsigned int i; } v; v.f = x;
    unsigned int lsb = (v.i >> 16) & 1;
    v.i += 0x7fff + lsb;                      // RNE to bf16
    return (unsigned short)(v.i >> 16);
}
__device__ __forceinline__ float bf2f(unsigned short u){
    union { unsigned int i; float f; } v; v.i = ((unsigned int)u) << 16; return v.f;
}
__device__ __forceinline__ float sspf(float x){
    return fmaxf(x, 0.0f) + log1pf(__expf(-fabsf(x))) - 0.69314718055994530942f;
}

// ---------------- counting sort of edges by dst ------------------------------
__global__ __launch_bounds__(256) void zero_cnt_kernel(){
    int i = blockIdx.x * 256 + threadIdx.x;
    g_cnt[i] = 0;                                   // NPAD exact
    if (blockIdx.x == 0 && threadIdx.x < NGRAPHS) g_gout[threadIdx.x] = 0.0f;
}
__global__ __launch_bounds__(256) void hist_kernel(const int* __restrict__ dst){
    int e = blockIdx.x * 256 + threadIdx.x;         // 2500*256 exact
    atomicAdd(&g_cnt[dst[e]], 1);
}
__global__ __launch_bounds__(256) void scan1_kernel(){
    __shared__ int s[256];
    int b = blockIdx.x, t = threadIdx.x, i = b * 256 + t;
    int c = g_cnt[i];
    s[t] = c; __syncthreads();
    #pragma unroll
    for (int off = 1; off < 256; off <<= 1){
        int v = (t >= off) ? s[t - off] : 0; __syncthreads();
        s[t] += v; __syncthreads();
    }
    g_ex[i] = s[t] - c;
    if (t == 255) g_part[b] = s[255];
}
__global__ __launch_bounds__(256) void scan2_kernel(){
    __shared__ int s[256];
    int t = threadIdx.x;
    s[t] = (t < 196) ? g_part[t] : 0; __syncthreads();
    #pragma unroll
    for (int off = 1; off < 256; off <<= 1){
        int v = (t >= off) ? s[t - off] : 0; __syncthreads();
        s[t] += v; __syncthreads();
    }
    g_part[t] = s[t];
}
__global__ __launch_bounds__(256) void scan3_kernel(){
    int b = blockIdx.x, i = b * 256 + threadIdx.x;
    g_row[i] = g_ex[i] + (b > 0 ? g_part[b - 1] : 0);
}
__global__ __launch_bounds__(256) void scatter_kernel(
    const float* __restrict__ pos, const int* __restrict__ src,
    const int* __restrict__ dst)
{
    int e = blockIdx.x * 256 + threadIdx.x;         // exact
    int sv = src[e], dv = dst[e];
    float dx = pos[3*dv]   - pos[3*sv];
    float dy = pos[3*dv+1] - pos[3*sv+1];
    float dz = pos[3*dv+2] - pos[3*sv+2];
    float d = sqrtf(dx*dx + dy*dy + dz*dz);         // < sqrt(3) < DMAX
    int p = atomicAdd(&g_row[dv], 1);               // g_row[v] ends at end-offset
    g_ssrc[p] = sv;
    g_sx[p]   = d * ((float)(NT - 1) / DMAX);
}

// ---------------- per-layer filter table: T[i] = W(d_i) * C(d_i) ------------
__global__ __launch_bounds__(128) void table_kernel(
    const float* __restrict__ w1g, const float* __restrict__ b1g,
    const float* __restrict__ w2g, const float* __restrict__ b2g)
{
    int l = blockIdx.x >> 11, pt = blockIdx.x & (NT - 1);
    int n = threadIdx.x;
    float d = pt * (DMAX / (float)(NT - 1));
    __shared__ float ea[64];
    __shared__ float tm[128];
    if (n < 50){
        float srel = d * 0.2f;
        float env = expf(1.0f - 1.0f / (1.0f - srel * srel));
        const float step = 5.0f / 49.0f;
        float dd = d - step * (float)n;
        ea[n] = expf((-0.5f / (step * step)) * dd * dd) * env;
    }
    __syncthreads();
    float acc = b1g[l * 128 + n];
    #pragma unroll 10
    for (int k = 0; k < 50; k++)
        acc = fmaf(ea[k], w1g[(l * 50 + k) * 128 + n], acc);
    tm[n] = sspf(acc);
    __syncthreads();
    float acc2 = b2g[l * 128 + n];
    #pragma unroll 8
    for (int k = 0; k < 128; k++)
        acc2 = fmaf(tm[k], w2g[(l * 128 + k) * 128 + n], acc2);
    float C = 0.5f * (cosf(d * 0.62831853071795864769f) + 1.0f);
    g_table[(l * NT + pt) * 128 + n] = acc2 * C;
}

// ---------------- weight prep: bf16 transpose of 9 node matrices ------------
__global__ __launch_bounds__(256) void wprep_kernel(
    const float* __restrict__ c1, const float* __restrict__ c2,
    const float* __restrict__ lw)
{
    int gid = blockIdx.x * 256 + threadIdx.x;       // 576*256 = 147456 exact
    int mat = gid >> 14, r = gid & 16383;
    int n = r & 127, k = r >> 7;
    int l = mat / 3, w = mat % 3;
    const float* base = (w == 0 ? c1 : w == 1 ? c2 : lw) + (size_t)l * HID * HID;
    g_wT[(size_t)mat * HID * HID + n * 128 + k] = f2bfbits(base[k * 128 + n]);
}

// ---------------- h init ----------------------------------------------------
__global__ __launch_bounds__(256) void hinit_kernel(
    const int* __restrict__ z, const float* __restrict__ emb)
{
    int idx = blockIdx.x * 256 + threadIdx.x;
    if (idx >= N_NODES * HID) return;
    int n = idx >> 7, f = idx & 127;
    g_h[idx] = emb[z[n] * HID + f];
}

// ---------------- node GEMM via MFMA, full K=128 ----------------------------
// in_sel: 0 = g_h (f32), 1 = g_xfb (bf16), 2 = g_aggb (bf16)
// mode 0: g_xfb = X@W        mode 2: g_xfb = ssp(X@W + bias)
// mode 1: g_h += X@W + bias
__global__ __launch_bounds__(256) void node_gemm_kernel(
    int in_sel, int mat, const float* __restrict__ bias, int mode)
{
    __shared__ __align__(16) unsigned short s_w[HID * 128];   // 32 KB bf16 [n][k]
    __shared__ __align__(16) unsigned short a_s[32 * 128];    // 8 KB bf16 nodes
    __shared__ __align__(16) float s_b[128];
    int tid = threadIdx.x;
    const unsigned short* wsrc = g_wT + (size_t)mat * HID * HID;
    for (int i = tid; i < 2048; i += 256){           // swizzled weight stage
        int n = i >> 4, c = i & 15, phys = c ^ (n & 15);
        *(uint4*)&s_w[n * 128 + phys * 8] = *(const uint4*)&wsrc[n * 128 + c * 8];
    }
    if (tid < 128) s_b[tid] = bias ? bias[tid] : 0.0f;

    int wave = tid >> 6, lane = tid & 63, quad = lane >> 4, l16 = lane & 15;
    int mtile = (wave & 1) * 16, nbase = (wave >> 1) * 64;
    const unsigned short* inb = (in_sel == 1) ? g_xfb : g_aggb;

    for (int t = blockIdx.x; t < NTILES; t += gridDim.x){
        int base = t * 32;
        __syncthreads();                             // a_s free (s_w ready, 1st iter)
        if (in_sel == 0){
            for (int i = tid; i < 512; i += 256){    // f32 -> bf16 staging
                int nn = i >> 4, c = i & 15, node = base + nn;
                int phys = c ^ (nn & 15);
                uint4 q = {0u, 0u, 0u, 0u};
                if (node < N_NODES){
                    const float* p = &g_h[(size_t)node * 128 + c * 8];
                    float4 f0 = *(const float4*)p;
                    float4 f1 = *(const float4*)(p + 4);
                    q.x = (unsigned int)f2bfbits(f0.x) | ((unsigned int)f2bfbits(f0.y) << 16);
                    q.y = (unsigned int)f2bfbits(f0.z) | ((unsigned int)f2bfbits(f0.w) << 16);
                    q.z = (unsigned int)f2bfbits(f1.x) | ((unsigned int)f2bfbits(f1.y) << 16);
                    q.w = (unsigned int)f2bfbits(f1.z) | ((unsigned int)f2bfbits(f1.w) << 16);
                }
                *(uint4*)&a_s[nn * 128 + phys * 8] = q;
            }
        } else {
            for (int i = tid; i < 512; i += 256){    // direct bf16 staging
                int nn = i >> 4, c = i & 15, node = base + nn;
                int phys = c ^ (nn & 15);
                uint4 q = {0u, 0u, 0u, 0u};
                if (node < N_NODES)
                    q = *(const uint4*)&inb[(size_t)node * 128 + c * 8];
                *(uint4*)&a_s[nn * 128 + phys * 8] = q;
            }
        }
        __syncthreads();

        bf16x8 av[4];
        int arow = mtile + l16;
        #pragma unroll
        for (int ks = 0; ks < 4; ks++){
            int phys = (ks * 4 + quad) ^ (arow & 15);
            av[ks] = *(const bf16x8*)&a_s[arow * 128 + phys * 8];
        }
        f32x4 acc[4] = {};
        #pragma unroll
        for (int nt = 0; nt < 4; nt++){
            int n = nbase + nt * 16 + l16;
            #pragma unroll
            for (int ks = 0; ks < 4; ks++){
                int phys = (ks * 4 + quad) ^ (n & 15);
                bf16x8 bv = *(const bf16x8*)&s_w[n * 128 + phys * 8];
                acc[nt] = __builtin_amdgcn_mfma_f32_16x16x32_bf16(av[ks], bv, acc[nt], 0, 0, 0);
            }
        }
        #pragma unroll
        for (int nt = 0; nt < 4; nt++){
            int n = nbase + nt * 16 + l16;
            float bb = s_b[n];
            #pragma unroll
            for (int r = 0; r < 4; r++){
                int node = base + mtile + quad * 4 + r;
                if (node >= N_NODES) continue;
                size_t o = (size_t)node * 128 + n;
                float v = acc[nt][r];
                if (mode == 0)      g_xfb[o] = f2bfbits(v);
                else if (mode == 2) g_xfb[o] = f2bfbits(sspf(v + bb));
                else                g_h[o] = g_h[o] + v + bb;
            }
        }
    }
}

// ---------------- CSR edge aggregation (table lookup, no atomics) -----------
// group (128 threads) g handles nodes [g*10, g*10+10); edges dst-sorted.
__global__ __launch_bounds__(256) void agg_kernel(int l){
    const float* __restrict__ T = g_table + (size_t)l * NT * 128;
    int tid = threadIdx.x;
    int half = tid >> 7, n = tid & 127;
    int v0 = (blockIdx.x * 2 + half) * 10;          // 2500 blocks -> 50000 exact
    for (int vi = 0; vi < 10; vi++){
        int v = v0 + vi;
        int e1 = g_row[v];
        int e0 = e1 - g_cnt[v];
        float acc = 0.0f;
        int j = e0;
        for (; j + 4 <= e1; j += 4){
            int   sa = g_ssrc[j],   sb = g_ssrc[j+1];
            int   sc = g_ssrc[j+2], sd = g_ssrc[j+3];
            float xa = g_sx[j],     xb = g_sx[j+1];
            float xc = g_sx[j+2],   xd = g_sx[j+3];
            int ia = (int)xa, ib = (int)xb, ic = (int)xc, id = (int)xd;
            float fa = xa - (float)ia, fb = xb - (float)ib;
            float fc = xc - (float)ic, fd = xd - (float)id;
            float ta0 = T[(size_t)ia * 128 + n], ta1 = T[(size_t)(ia + 1) * 128 + n];
            float tb0 = T[(size_t)ib * 128 + n], tb1 = T[(size_t)(ib + 1) * 128 + n];
            float tc0 = T[(size_t)ic * 128 + n], tc1 = T[(size_t)(ic + 1) * 128 + n];
            float td0 = T[(size_t)id * 128 + n], td1 = T[(size_t)(id + 1) * 128 + n];
            float ga = bf2f(g_xfb[(size_t)sa * 128 + n]);
            float gb = bf2f(g_xfb[(size_t)sb * 128 + n]);
            float gc = bf2f(g_xfb[(size_t)sc * 128 + n]);
            float gd = bf2f(g_xfb[(size_t)sd * 128 + n]);
            acc = fmaf(fmaf(fa, ta1 - ta0, ta0), ga, acc);
            acc = fmaf(fmaf(fb, tb1 - tb0, tb0), gb, acc);
            acc = fmaf(fmaf(fc, tc1 - tc0, tc0), gc, acc);
            acc = fmaf(fmaf(fd, td1 - td0, td0), gd, acc);
        }
        for (; j < e1; j++){
            int s = g_ssrc[j]; float x = g_sx[j];
            int i0 = (int)x; float fr = x - (float)i0;
            float t0 = T[(size_t)i0 * 128 + n], t1 = T[(size_t)(i0 + 1) * 128 + n];
            acc = fmaf(fmaf(fr, t1 - t0, t0), bf2f(g_xfb[(size_t)s * 128 + n]), acc);
        }
        g_aggb[(size_t)v * 128 + n] = f2bfbits(acc);  // plain store (covers deg-0)
    }
}

// ---------------- output head: per-node energy (no atomics) -----------------
__global__ __launch_bounds__(256) void head_kernel(
    const float* __restrict__ w1g, const float* __restrict__ b1g,
    const float* __restrict__ w2g, const float* __restrict__ b2g)
{
    __shared__ __align__(16) float w1h[128 * 64];   // 32 KB
    __shared__ __align__(16) float w2h[64];
    __shared__ __align__(16) float b1h[64];
    __shared__ __align__(16) float hrow[4][128];
    int tid = threadIdx.x;
    for (int i = tid; i < 128 * 64 / 4; i += 256)
        *(float4*)&w1h[i * 4] = *(const float4*)&w1g[i * 4];
    if (tid < 64){ w2h[tid] = w2g[tid]; b1h[tid] = b1g[tid]; }
    float sb2 = b2g[0];
    __syncthreads();
    int wave = tid >> 6, lane = tid & 63;
    for (int nb = blockIdx.x * 4; nb < N_NODES; nb += gridDim.x * 4){
        int node = nb + wave;
        __syncthreads();
        if (node < N_NODES){
            hrow[wave][lane]      = g_h[(size_t)node * 128 + lane];
            hrow[wave][64 + lane] = g_h[(size_t)node * 128 + 64 + lane];
        }
        __syncthreads();
        if (node < N_NODES){
            float acc = b1h[lane];
            #pragma unroll 8
            for (int k = 0; k < 128; k++)
                acc = fmaf(hrow[wave][k], w1h[k * 64 + lane], acc);
            acc = sspf(acc) * w2h[lane];
            #pragma unroll
            for (int off = 32; off > 0; off >>= 1) acc += __shfl_down(acc, off, 64);
            if (lane == 0) g_sx[node] = acc + sb2;   // reuse g_sx as e_atom
        }
    }
}

// ---------------- segment-sum of e_atom with LDS pre-reduction --------------
__global__ __launch_bounds__(256) void reduce_kernel(const int* __restrict__ batch){
    __shared__ float part[NGRAPHS];
    int tid = threadIdx.x;
    if (tid < NGRAPHS) part[tid] = 0.0f;
    __syncthreads();
    int i = blockIdx.x * 256 + tid;                 // 196 blocks
    if (i < N_NODES) atomicAdd(&part[batch[i]], g_sx[i]);
    __syncthreads();
    if (tid < NGRAPHS && part[tid] != 0.0f)
        __hip_atomic_fetch_add(&g_gout[tid], part[tid],
                               __ATOMIC_RELAXED, __HIP_MEMORY_SCOPE_AGENT);
}

__global__ void store_kernel(float* __restrict__ out){
    int i = threadIdx.x;
    if (i < NGRAPHS) out[i] = g_gout[i];
}

extern "C" void kernel_launch(void* const* d_in, const int* in_sizes, int n_in,
                              void* d_out, int out_size, void* d_ws, size_t ws_size,
                              hipStream_t stream)
{
    const int* z       = (const int*)d_in[0];
    const float* pos   = (const float*)d_in[1];
    const int* ei      = (const int*)d_in[2];
    const int* src = ei;
    const int* dst = ei + N_EDGES;
    const int* batch   = (const int*)d_in[3];
    const float* emb     = (const float*)d_in[4];
    const float* mlp_w1  = (const float*)d_in[5];
    const float* mlp_b1  = (const float*)d_in[6];
    const float* mlp_w2  = (const float*)d_in[7];
    const float* mlp_b2  = (const float*)d_in[8];
    const float* conv1_w = (const float*)d_in[9];
    const float* conv2_w = (const float*)d_in[10];
    const float* conv2_b = (const float*)d_in[11];
    const float* lin_w   = (const float*)d_in[12];
    const float* lin_b   = (const float*)d_in[13];
    const float* out1_w  = (const float*)d_in[14];
    const float* out1_b  = (const float*)d_in[15];
    const float* out2_w  = (const float*)d_in[16];
    const float* out2_b  = (const float*)d_in[17];
    (void)d_ws; (void)ws_size; (void)in_sizes; (void)n_in; (void)out_size;

    // --- one-time: sort edges by dst (CSR), tables, weight prep, h0 ---
    zero_cnt_kernel<<<196, 256, 0, stream>>>();
    hist_kernel<<<2500, 256, 0, stream>>>(dst);
    scan1_kernel<<<196, 256, 0, stream>>>();
    scan2_kernel<<<1, 256, 0, stream>>>();
    scan3_kernel<<<196, 256, 0, stream>>>();
    scatter_kernel<<<2500, 256, 0, stream>>>(pos, src, dst);
    table_kernel<<<NL * NT, 128, 0, stream>>>(mlp_w1, mlp_b1, mlp_w2, mlp_b2);
    wprep_kernel<<<576, 256, 0, stream>>>(conv1_w, conv2_w, lin_w);
    hinit_kernel<<<(N_NODES * HID + 255) / 256, 256, 0, stream>>>(z, emb);

    for (int l = 0; l < NL; l++){
        node_gemm_kernel<<<521, 256, 0, stream>>>(0, l * 3 + 0, nullptr, 0);       // xfb = h@c1
        agg_kernel<<<2500, 256, 0, stream>>>(l);                                    // aggb
        node_gemm_kernel<<<521, 256, 0, stream>>>(2, l * 3 + 1,                     // xfb = ssp(aggb@c2+b)
                                                  conv2_b + (size_t)l * HID, 2);
        node_gemm_kernel<<<521, 256, 0, stream>>>(1, l * 3 + 2,                     // h += xfb@lw+b
                                                  lin_b + (size_t)l * HID, 1);
    }

    head_kernel<<<512, 256, 0, stream>>>(out1_w, out1_b, out2_w, out2_b);
    reduce_kernel<<<196, 256, 0, stream>>>(batch);
    store_kernel<<<1, 64, 0, stream>>>((float*)d_out);
}

// Round 8
// 668.346 us; speedup vs baseline: 4.2916x; 1.0959x over previous
//
#include <hip/hip_runtime.h>
#include <math.h>

#define N_NODES 50000
#define N_EDGES 640000
#define HID 128
#define NL 3
#define NGRAPHS 64
#define NT 2048
#define DMAX 1.7330f
#define NPAD 50176   // 196*256
#define NTILES 1563  // ceil(50000/32)

typedef __attribute__((ext_vector_type(8))) short bf16x8;
typedef __attribute__((ext_vector_type(4))) float f32x4;

// ---------------- module-scope device buffers -------------------------------
__device__ __align__(16) float g_h  [N_NODES * HID];           // f32 node features
__device__ __align__(16) unsigned short g_xfb [N_NODES * HID]; // bf16 xf
__device__ __align__(16) unsigned short g_aggb[N_NODES * HID]; // bf16 aggregation
__device__ __align__(16) float g_table[NL * NT * HID];         // W(d)*C(d)
__device__ __align__(16) unsigned short g_wT[9 * HID * HID];   // bf16 [n][k]
__device__ __align__(16) int   g_cnt[NPAD];
__device__ __align__(16) int   g_ex [NPAD];
__device__ __align__(16) int   g_row[NPAD];
__device__ __align__(16) int   g_part[256];
__device__ __align__(16) int   g_ssrc[N_EDGES];
__device__ __align__(16) float g_sx  [N_EDGES];                // d*INVH; later e_atom
__device__ __align__(16) float g_gout[NGRAPHS];

__device__ __forceinline__ unsigned short f2bfbits(float x){
    union { float f; unsigned int i; } v; v.f = x;
    unsigned int lsb = (v.i >> 16) & 1;
    v.i += 0x7fff + lsb;                      // RNE to bf16
    return (unsigned short)(v.i >> 16);
}
__device__ __forceinline__ float bf2f(unsigned short u){
    union { unsigned int i; float f; } v; v.i = ((unsigned int)u) << 16; return v.f;
}
__device__ __forceinline__ float sspf(float x){
    return fmaxf(x, 0.0f) + log1pf(__expf(-fabsf(x))) - 0.69314718055994530942f;
}

// ---------------- counting sort of edges by dst ------------------------------
__global__ __launch_bounds__(256) void zero_cnt_kernel(){
    int i = blockIdx.x * 256 + threadIdx.x;
    g_cnt[i] = 0;                                   // NPAD exact
    if (blockIdx.x == 0 && threadIdx.x < NGRAPHS) g_gout[threadIdx.x] = 0.0f;
}
__global__ __launch_bounds__(256) void hist_kernel(const int* __restrict__ dst){
    int e = blockIdx.x * 256 + threadIdx.x;         // 2500*256 exact
    atomicAdd(&g_cnt[dst[e]], 1);
}
__global__ __launch_bounds__(256) void scan1_kernel(){
    __shared__ int s[256];
    int b = blockIdx.x, t = threadIdx.x, i = b * 256 + t;
    int c = g_cnt[i];
    s[t] = c; __syncthreads();
    #pragma unroll
    for (int off = 1; off < 256; off <<= 1){
        int v = (t >= off) ? s[t - off] : 0; __syncthreads();
        s[t] += v; __syncthreads();
    }
    g_ex[i] = s[t] - c;
    if (t == 255) g_part[b] = s[255];
}
__global__ __launch_bounds__(256) void scan2_kernel(){
    __shared__ int s[256];
    int t = threadIdx.x;
    s[t] = (t < 196) ? g_part[t] : 0; __syncthreads();
    #pragma unroll
    for (int off = 1; off < 256; off <<= 1){
        int v = (t >= off) ? s[t - off] : 0; __syncthreads();
        s[t] += v; __syncthreads();
    }
    g_part[t] = s[t];
}
__global__ __launch_bounds__(256) void scan3_kernel(){
    int b = blockIdx.x, i = b * 256 + threadIdx.x;
    g_row[i] = g_ex[i] + (b > 0 ? g_part[b - 1] : 0);
}
__global__ __launch_bounds__(256) void scatter_kernel(
    const float* __restrict__ pos, const int* __restrict__ src,
    const int* __restrict__ dst)
{
    int e = blockIdx.x * 256 + threadIdx.x;         // exact
    int sv = src[e], dv = dst[e];
    float dx = pos[3*dv]   - pos[3*sv];
    float dy = pos[3*dv+1] - pos[3*sv+1];
    float dz = pos[3*dv+2] - pos[3*sv+2];
    float d = sqrtf(dx*dx + dy*dy + dz*dz);         // < sqrt(3) < DMAX
    int p = atomicAdd(&g_row[dv], 1);               // g_row[v] ends at end-offset
    g_ssrc[p] = sv;
    g_sx[p]   = d * ((float)(NT - 1) / DMAX);
}

// ---------------- per-layer filter table: T[i] = W(d_i) * C(d_i) ------------
__global__ __launch_bounds__(128) void table_kernel(
    const float* __restrict__ w1g, const float* __restrict__ b1g,
    const float* __restrict__ w2g, const float* __restrict__ b2g)
{
    int l = blockIdx.x >> 11, pt = blockIdx.x & (NT - 1);
    int n = threadIdx.x;
    float d = pt * (DMAX / (float)(NT - 1));
    __shared__ float ea[64];
    __shared__ float tm[128];
    if (n < 50){
        float srel = d * 0.2f;
        float env = expf(1.0f - 1.0f / (1.0f - srel * srel));
        const float step = 5.0f / 49.0f;
        float dd = d - step * (float)n;
        ea[n] = expf((-0.5f / (step * step)) * dd * dd) * env;
    }
    __syncthreads();
    float acc = b1g[l * 128 + n];
    #pragma unroll 10
    for (int k = 0; k < 50; k++)
        acc = fmaf(ea[k], w1g[(l * 50 + k) * 128 + n], acc);
    tm[n] = sspf(acc);
    __syncthreads();
    float acc2 = b2g[l * 128 + n];
    #pragma unroll 8
    for (int k = 0; k < 128; k++)
        acc2 = fmaf(tm[k], w2g[(l * 128 + k) * 128 + n], acc2);
    float C = 0.5f * (cosf(d * 0.62831853071795864769f) + 1.0f);
    g_table[(l * NT + pt) * 128 + n] = acc2 * C;
}

// ---------------- weight prep: bf16 transpose of 9 node matrices ------------
__global__ __launch_bounds__(256) void wprep_kernel(
    const float* __restrict__ c1, const float* __restrict__ c2,
    const float* __restrict__ lw)
{
    int gid = blockIdx.x * 256 + threadIdx.x;       // 576*256 = 147456 exact
    int mat = gid >> 14, r = gid & 16383;
    int n = r & 127, k = r >> 7;
    int l = mat / 3, w = mat % 3;
    const float* base = (w == 0 ? c1 : w == 1 ? c2 : lw) + (size_t)l * HID * HID;
    g_wT[(size_t)mat * HID * HID + n * 128 + k] = f2bfbits(base[k * 128 + n]);
}

// ---------------- layer-0 conv1: emb gather + h init + GEMM -----------------
__global__ __launch_bounds__(256) void conv1_kernel(
    const int* __restrict__ z, const float* __restrict__ emb)
{
    __shared__ __align__(16) unsigned short s_w[HID * 128];   // 32 KB c1(l0)
    __shared__ __align__(16) unsigned short a_s[32 * 128];    // 8 KB
    __shared__ int zl[32];
    int tid = threadIdx.x;
    for (int i = tid; i < 2048; i += 256){
        int n = i >> 4, c = i & 15, phys = c ^ (n & 15);
        *(uint4*)&s_w[n * 128 + phys * 8] = *(const uint4*)&g_wT[n * 128 + c * 8];
    }
    int wave = tid >> 6, lane = tid & 63, quad = lane >> 4, l16 = lane & 15;
    int mtile = (wave & 1) * 16, nbase = (wave >> 1) * 64;
    for (int t = blockIdx.x; t < NTILES; t += gridDim.x){
        int base = t * 32;
        __syncthreads();
        if (tid < 32) zl[tid] = (base + tid < N_NODES) ? z[base + tid] : 0;
        __syncthreads();
        for (int i = tid; i < 512; i += 256){
            int nn = i >> 4, c = i & 15, node = base + nn;
            int phys = c ^ (nn & 15);
            uint4 q = {0u, 0u, 0u, 0u};
            if (node < N_NODES){
                const float* p = &emb[(size_t)zl[nn] * 128 + c * 8];
                float4 f0 = *(const float4*)p;
                float4 f1 = *(const float4*)(p + 4);
                *(float4*)&g_h[(size_t)node * 128 + c * 8]     = f0;
                *(float4*)&g_h[(size_t)node * 128 + c * 8 + 4] = f1;
                q.x = (unsigned int)f2bfbits(f0.x) | ((unsigned int)f2bfbits(f0.y) << 16);
                q.y = (unsigned int)f2bfbits(f0.z) | ((unsigned int)f2bfbits(f0.w) << 16);
                q.z = (unsigned int)f2bfbits(f1.x) | ((unsigned int)f2bfbits(f1.y) << 16);
                q.w = (unsigned int)f2bfbits(f1.z) | ((unsigned int)f2bfbits(f1.w) << 16);
            }
            *(uint4*)&a_s[nn * 128 + phys * 8] = q;
        }
        __syncthreads();
        bf16x8 av[4];
        int arow = mtile + l16;
        #pragma unroll
        for (int ks = 0; ks < 4; ks++){
            int phys = (ks * 4 + quad) ^ (arow & 15);
            av[ks] = *(const bf16x8*)&a_s[arow * 128 + phys * 8];
        }
        f32x4 acc[4] = {};
        #pragma unroll
        for (int nt = 0; nt < 4; nt++){
            int n = nbase + nt * 16 + l16;
            #pragma unroll
            for (int ks = 0; ks < 4; ks++){
                int phys = (ks * 4 + quad) ^ (n & 15);
                bf16x8 bv = *(const bf16x8*)&s_w[n * 128 + phys * 8];
                acc[nt] = __builtin_amdgcn_mfma_f32_16x16x32_bf16(av[ks], bv, acc[nt], 0, 0, 0);
            }
        }
        #pragma unroll
        for (int nt = 0; nt < 4; nt++){
            int n = nbase + nt * 16 + l16;
            #pragma unroll
            for (int r = 0; r < 4; r++){
                int node = base + mtile + quad * 4 + r;
                if (node < N_NODES)
                    g_xfb[(size_t)node * 128 + n] = f2bfbits(acc[nt][r]);
            }
        }
    }
}

// ---------------- fused per-layer GEMM chain --------------------------------
// t = ssp(aggb@c2 + b2); h += t@lw + lb; if(!skip3) xfb = bf16(h)@c1next
__global__ __launch_bounds__(256) void fused_kernel(
    int l, const float* __restrict__ bias2, const float* __restrict__ biasl,
    int skip3)
{
    __shared__ __align__(16) unsigned short s_w[HID * 128];   // 32 KB c2 swizzled
    __shared__ __align__(16) unsigned short a_s[32 * 128];    // 8 KB aggb tile
    __shared__ __align__(16) unsigned short t_s[32 * 128];    // 8 KB t tile
    __shared__ __align__(16) unsigned short hb_s[32 * 128];   // 8 KB h-bf16 tile
    __shared__ __align__(16) float s_b2[128];
    __shared__ __align__(16) float s_bl[128];
    int tid = threadIdx.x;
    const unsigned short* c2  = g_wT + (size_t)(l * 3 + 1) * HID * HID;
    const unsigned short* lw  = g_wT + (size_t)(l * 3 + 2) * HID * HID;
    const unsigned short* c1n = g_wT + (size_t)((l + 1) * 3) * HID * HID;
    for (int i = tid; i < 2048; i += 256){
        int n = i >> 4, c = i & 15, phys = c ^ (n & 15);
        *(uint4*)&s_w[n * 128 + phys * 8] = *(const uint4*)&c2[n * 128 + c * 8];
    }
    if (tid < 128){ s_b2[tid] = bias2[tid]; s_bl[tid] = biasl[tid]; }

    int wave = tid >> 6, lane = tid & 63, quad = lane >> 4, l16 = lane & 15;
    int mtile = (wave & 1) * 16, nbase = (wave >> 1) * 64;

    for (int t = blockIdx.x; t < NTILES; t += gridDim.x){
        int base = t * 32;
        __syncthreads();
        for (int i = tid; i < 512; i += 256){        // stage aggb tile
            int nn = i >> 4, c = i & 15, node = base + nn;
            int phys = c ^ (nn & 15);
            uint4 q = {0u, 0u, 0u, 0u};
            if (node < N_NODES)
                q = *(const uint4*)&g_aggb[(size_t)node * 128 + c * 8];
            *(uint4*)&a_s[nn * 128 + phys * 8] = q;
        }
        __syncthreads();

        // ---- GEMM1: acc = aggb @ c2
        int arow = mtile + l16;
        bf16x8 av[4];
        #pragma unroll
        for (int ks = 0; ks < 4; ks++){
            int phys = (ks * 4 + quad) ^ (arow & 15);
            av[ks] = *(const bf16x8*)&a_s[arow * 128 + phys * 8];
        }
        f32x4 acc[4] = {};
        #pragma unroll
        for (int nt = 0; nt < 4; nt++){
            int n = nbase + nt * 16 + l16;
            #pragma unroll
            for (int ks = 0; ks < 4; ks++){
                int phys = (ks * 4 + quad) ^ (n & 15);
                bf16x8 bv = *(const bf16x8*)&s_w[n * 128 + phys * 8];
                acc[nt] = __builtin_amdgcn_mfma_f32_16x16x32_bf16(av[ks], bv, acc[nt], 0, 0, 0);
            }
        }
        // epilogue1: t = ssp(acc + b2) -> t_s (swizzled scalar stores)
        #pragma unroll
        for (int nt = 0; nt < 4; nt++){
            int n = nbase + nt * 16 + l16;
            float bb = s_b2[n];
            int cch = n >> 3, jj = n & 7;
            #pragma unroll
            for (int r = 0; r < 4; r++){
                int row = mtile + quad * 4 + r;
                t_s[row * 128 + ((cch ^ (row & 15)) << 3) + jj] =
                    f2bfbits(sspf(acc[nt][r] + bb));
            }
        }
        __syncthreads();

        // ---- GEMM2: acc2 = t @ lw  (B streamed from L2)
        #pragma unroll
        for (int ks = 0; ks < 4; ks++){
            int phys = (ks * 4 + quad) ^ (arow & 15);
            av[ks] = *(const bf16x8*)&t_s[arow * 128 + phys * 8];
        }
        f32x4 acc2[4] = {};
        #pragma unroll
        for (int nt = 0; nt < 4; nt++){
            int n = nbase + nt * 16 + l16;
            #pragma unroll
            for (int ks = 0; ks < 4; ks++){
                bf16x8 bv = *(const bf16x8*)&lw[n * 128 + ks * 32 + quad * 8];
                acc2[nt] = __builtin_amdgcn_mfma_f32_16x16x32_bf16(av[ks], bv, acc2[nt], 0, 0, 0);
            }
        }
        // epilogue2: h += acc2 + lb; stash bf16(h) for GEMM3
        #pragma unroll
        for (int nt = 0; nt < 4; nt++){
            int n = nbase + nt * 16 + l16;
            float bb = s_bl[n];
            int cch = n >> 3, jj = n & 7;
            #pragma unroll
            for (int r = 0; r < 4; r++){
                int row = mtile + quad * 4 + r;
                int node = base + row;
                if (node >= N_NODES) continue;
                size_t o = (size_t)node * 128 + n;
                float hv = g_h[o] + acc2[nt][r] + bb;
                g_h[o] = hv;
                if (!skip3)
                    hb_s[row * 128 + ((cch ^ (row & 15)) << 3) + jj] = f2bfbits(hv);
            }
        }
        if (skip3) continue;
        __syncthreads();

        // ---- GEMM3: xfb = bf16(h) @ c1next  (B streamed from L2)
        #pragma unroll
        for (int ks = 0; ks < 4; ks++){
            int phys = (ks * 4 + quad) ^ (arow & 15);
            av[ks] = *(const bf16x8*)&hb_s[arow * 128 + phys * 8];
        }
        f32x4 acc3[4] = {};
        #pragma unroll
        for (int nt = 0; nt < 4; nt++){
            int n = nbase + nt * 16 + l16;
            #pragma unroll
            for (int ks = 0; ks < 4; ks++){
                bf16x8 bv = *(const bf16x8*)&c1n[n * 128 + ks * 32 + quad * 8];
                acc3[nt] = __builtin_amdgcn_mfma_f32_16x16x32_bf16(av[ks], bv, acc3[nt], 0, 0, 0);
            }
        }
        #pragma unroll
        for (int nt = 0; nt < 4; nt++){
            int n = nbase + nt * 16 + l16;
            #pragma unroll
            for (int r = 0; r < 4; r++){
                int node = base + mtile + quad * 4 + r;
                if (node < N_NODES)
                    g_xfb[(size_t)node * 128 + n] = f2bfbits(acc3[nt][r]);
            }
        }
    }
}

// ---------------- CSR edge aggregation v3: 32 thr/node x 4 ch/thr -----------
__global__ __launch_bounds__(256) void agg_kernel(int l){
    const float* __restrict__ T = g_table + (size_t)l * NT * 128;
    int tid = threadIdx.x;
    int grp = tid >> 5, n0 = (tid & 31) * 4;
    int v = blockIdx.x * 8 + grp;                   // 6250 blocks * 8 = 50000 exact
    int e1 = g_row[v];
    int e0 = e1 - g_cnt[v];
    float a0 = 0.f, a1 = 0.f, a2 = 0.f, a3 = 0.f;
    int j = e0;
    for (; j + 2 <= e1; j += 2){
        int   sA = g_ssrc[j],  sB = g_ssrc[j+1];
        float xA = g_sx[j],    xB = g_sx[j+1];
        int iA = (int)xA, iB = (int)xB;
        float fA = xA - (float)iA, fB = xB - (float)iB;
        float4 tA0 = *(const float4*)&T[(size_t)iA * 128 + n0];
        float4 tA1 = *(const float4*)&T[(size_t)(iA + 1) * 128 + n0];
        float4 tB0 = *(const float4*)&T[(size_t)iB * 128 + n0];
        float4 tB1 = *(const float4*)&T[(size_t)(iB + 1) * 128 + n0];
        ushort4 gA = *(const ushort4*)&g_xfb[(size_t)sA * 128 + n0];
        ushort4 gB = *(const ushort4*)&g_xfb[(size_t)sB * 128 + n0];
        a0 = fmaf(fmaf(fA, tA1.x - tA0.x, tA0.x), bf2f(gA.x), a0);
        a1 = fmaf(fmaf(fA, tA1.y - tA0.y, tA0.y), bf2f(gA.y), a1);
        a2 = fmaf(fmaf(fA, tA1.z - tA0.z, tA0.z), bf2f(gA.z), a2);
        a3 = fmaf(fmaf(fA, tA1.w - tA0.w, tA0.w), bf2f(gA.w), a3);
        a0 = fmaf(fmaf(fB, tB1.x - tB0.x, tB0.x), bf2f(gB.x), a0);
        a1 = fmaf(fmaf(fB, tB1.y - tB0.y, tB0.y), bf2f(gB.y), a1);
        a2 = fmaf(fmaf(fB, tB1.z - tB0.z, tB0.z), bf2f(gB.z), a2);
        a3 = fmaf(fmaf(fB, tB1.w - tB0.w, tB0.w), bf2f(gB.w), a3);
    }
    if (j < e1){
        int s = g_ssrc[j]; float x = g_sx[j];
        int i0 = (int)x; float fr = x - (float)i0;
        float4 t0 = *(const float4*)&T[(size_t)i0 * 128 + n0];
        float4 t1 = *(const float4*)&T[(size_t)(i0 + 1) * 128 + n0];
        ushort4 g = *(const ushort4*)&g_xfb[(size_t)s * 128 + n0];
        a0 = fmaf(fmaf(fr, t1.x - t0.x, t0.x), bf2f(g.x), a0);
        a1 = fmaf(fmaf(fr, t1.y - t0.y, t0.y), bf2f(g.y), a1);
        a2 = fmaf(fmaf(fr, t1.z - t0.z, t0.z), bf2f(g.z), a2);
        a3 = fmaf(fmaf(fr, t1.w - t0.w, t0.w), bf2f(g.w), a3);
    }
    ushort4 o;
    o.x = f2bfbits(a0); o.y = f2bfbits(a1); o.z = f2bfbits(a2); o.w = f2bfbits(a3);
    *(ushort4*)&g_aggb[(size_t)v * 128 + n0] = o;
}

// ---------------- output head: per-node energy (no atomics) -----------------
__global__ __launch_bounds__(256) void head_kernel(
    const float* __restrict__ w1g, const float* __restrict__ b1g,
    const float* __restrict__ w2g, const float* __restrict__ b2g)
{
    __shared__ __align__(16) float w1h[128 * 64];   // 32 KB
    __shared__ __align__(16) float w2h[64];
    __shared__ __align__(16) float b1h[64];
    __shared__ __align__(16) float hrow[4][128];
    int tid = threadIdx.x;
    for (int i = tid; i < 128 * 64 / 4; i += 256)
        *(float4*)&w1h[i * 4] = *(const float4*)&w1g[i * 4];
    if (tid < 64){ w2h[tid] = w2g[tid]; b1h[tid] = b1g[tid]; }
    float sb2 = b2g[0];
    __syncthreads();
    int wave = tid >> 6, lane = tid & 63;
    for (int nb = blockIdx.x * 4; nb < N_NODES; nb += gridDim.x * 4){
        int node = nb + wave;
        __syncthreads();
        if (node < N_NODES){
            hrow[wave][lane]      = g_h[(size_t)node * 128 + lane];
            hrow[wave][64 + lane] = g_h[(size_t)node * 128 + 64 + lane];
        }
        __syncthreads();
        if (node < N_NODES){
            float acc = b1h[lane];
            #pragma unroll 8
            for (int k = 0; k < 128; k++)
                acc = fmaf(hrow[wave][k], w1h[k * 64 + lane], acc);
            acc = sspf(acc) * w2h[lane];
            #pragma unroll
            for (int off = 32; off > 0; off >>= 1) acc += __shfl_down(acc, off, 64);
            if (lane == 0) g_sx[node] = acc + sb2;   // reuse g_sx as e_atom
        }
    }
}

// ---------------- segment-sum of e_atom with LDS pre-reduction --------------
__global__ __launch_bounds__(256) void reduce_kernel(const int* __restrict__ batch){
    __shared__ float part[NGRAPHS];
    int tid = threadIdx.x;
    if (tid < NGRAPHS) part[tid] = 0.0f;
    __syncthreads();
    int i = blockIdx.x * 256 + tid;                 // 196 blocks
    if (i < N_NODES) atomicAdd(&part[batch[i]], g_sx[i]);
    __syncthreads();
    if (tid < NGRAPHS && part[tid] != 0.0f)
        __hip_atomic_fetch_add(&g_gout[tid], part[tid],
                               __ATOMIC_RELAXED, __HIP_MEMORY_SCOPE_AGENT);
}

__global__ void store_kernel(float* __restrict__ out){
    int i = threadIdx.x;
    if (i < NGRAPHS) out[i] = g_gout[i];
}

extern "C" void kernel_launch(void* const* d_in, const int* in_sizes, int n_in,
                              void* d_out, int out_size, void* d_ws, size_t ws_size,
                              hipStream_t stream)
{
    const int* z       = (const int*)d_in[0];
    const float* pos   = (const float*)d_in[1];
    const int* ei      = (const int*)d_in[2];
    const int* src = ei;
    const int* dst = ei + N_EDGES;
    const int* batch   = (const int*)d_in[3];
    const float* emb     = (const float*)d_in[4];
    const float* mlp_w1  = (const float*)d_in[5];
    const float* mlp_b1  = (const float*)d_in[6];
    const float* mlp_w2  = (const float*)d_in[7];
    const float* mlp_b2  = (const float*)d_in[8];
    const float* conv1_w = (const float*)d_in[9];
    const float* conv2_w = (const float*)d_in[10];
    const float* conv2_b = (const float*)d_in[11];
    const float* lin_w   = (const float*)d_in[12];
    const float* lin_b   = (const float*)d_in[13];
    const float* out1_w  = (const float*)d_in[14];
    const float* out1_b  = (const float*)d_in[15];
    const float* out2_w  = (const float*)d_in[16];
    const float* out2_b  = (const float*)d_in[17];
    (void)d_ws; (void)ws_size; (void)in_sizes; (void)n_in; (void)out_size;

    // --- one-time: CSR sort, tables, weight prep ---
    zero_cnt_kernel<<<196, 256, 0, stream>>>();
    hist_kernel<<<2500, 256, 0, stream>>>(dst);
    scan1_kernel<<<196, 256, 0, stream>>>();
    scan2_kernel<<<1, 256, 0, stream>>>();
    scan3_kernel<<<196, 256, 0, stream>>>();
    scatter_kernel<<<2500, 256, 0, stream>>>(pos, src, dst);
    table_kernel<<<NL * NT, 128, 0, stream>>>(mlp_w1, mlp_b1, mlp_w2, mlp_b2);
    wprep_kernel<<<576, 256, 0, stream>>>(conv1_w, conv2_w, lin_w);

    conv1_kernel<<<521, 256, 0, stream>>>(z, emb);   // h init + layer-0 conv1
    for (int l = 0; l < NL; l++){
        agg_kernel<<<6250, 256, 0, stream>>>(l);
        fused_kernel<<<521, 256, 0, stream>>>(l, conv2_b + (size_t)l * HID,
                                              lin_b + (size_t)l * HID, l == NL - 1);
    }

    head_kernel<<<512, 256, 0, stream>>>(out1_w, out1_b, out2_w, out2_b);
    reduce_kernel<<<196, 256, 0, stream>>>(batch);
    store_kernel<<<1, 64, 0, stream>>>((float*)d_out);
}

// Round 9
// 632.181 us; speedup vs baseline: 4.5371x; 1.0572x over previous
//
#include <hip/hip_runtime.h>
#include <math.h>

#define N_NODES 50000
#define N_EDGES 640000
#define HID 128
#define NL 3
#define NGRAPHS 64
#define NT 2048
#define DMAX 1.7330f
#define NPAD 50176   // 196*256
#define NTILES 1563  // ceil(50000/32)

typedef __attribute__((ext_vector_type(8))) short bf16x8;
typedef __attribute__((ext_vector_type(4))) float f32x4;

// ---------------- module-scope device buffers -------------------------------
__device__ __align__(16) float g_h  [N_NODES * HID];           // f32 node features
__device__ __align__(16) unsigned short g_xfb [N_NODES * HID]; // bf16 xf
__device__ __align__(16) unsigned short g_aggb[N_NODES * HID]; // bf16 aggregation
__device__ __align__(16) float g_table[NL * NT * HID];         // W(d)*C(d)
__device__ __align__(16) unsigned short g_wT[9 * HID * HID];   // bf16 [n][k]
__device__ __align__(16) int   g_cnt[NPAD];
__device__ __align__(16) int   g_ex [NPAD];
__device__ __align__(16) int   g_row[NPAD];
__device__ __align__(16) int   g_part[256];
__device__ __align__(16) int   g_ssrc[N_EDGES];
__device__ __align__(16) float g_sx  [N_EDGES];                // d*INVH; later e_atom
__device__ __align__(16) float g_gout[NGRAPHS];

__device__ __forceinline__ unsigned short f2bfbits(float x){
    union { float f; unsigned int i; } v; v.f = x;
    unsigned int lsb = (v.i >> 16) & 1;
    v.i += 0x7fff + lsb;                      // RNE to bf16
    return (unsigned short)(v.i >> 16);
}
__device__ __forceinline__ float bf2f(unsigned short u){
    union { unsigned int i; float f; } v; v.i = ((unsigned int)u) << 16; return v.f;
}
__device__ __forceinline__ float sspf(float x){
    return fmaxf(x, 0.0f) + log1pf(__expf(-fabsf(x))) - 0.69314718055994530942f;
}

// ---------------- counting sort of edges by dst ------------------------------
__global__ __launch_bounds__(256) void zero_cnt_kernel(){
    int i = blockIdx.x * 256 + threadIdx.x;
    g_cnt[i] = 0;                                   // NPAD exact
    if (blockIdx.x == 0 && threadIdx.x < NGRAPHS) g_gout[threadIdx.x] = 0.0f;
}
__global__ __launch_bounds__(256) void hist_kernel(const int* __restrict__ dst){
    int e = blockIdx.x * 256 + threadIdx.x;         // 2500*256 exact
    atomicAdd(&g_cnt[dst[e]], 1);
}
__global__ __launch_bounds__(256) void scan1_kernel(){
    __shared__ int s[256];
    int b = blockIdx.x, t = threadIdx.x, i = b * 256 + t;
    int c = g_cnt[i];
    s[t] = c; __syncthreads();
    #pragma unroll
    for (int off = 1; off < 256; off <<= 1){
        int v = (t >= off) ? s[t - off] : 0; __syncthreads();
        s[t] += v; __syncthreads();
    }
    g_ex[i] = s[t] - c;
    if (t == 255) g_part[b] = s[255];
}
__global__ __launch_bounds__(256) void scan2_kernel(){
    __shared__ int s[256];
    int t = threadIdx.x;
    s[t] = (t < 196) ? g_part[t] : 0; __syncthreads();
    #pragma unroll
    for (int off = 1; off < 256; off <<= 1){
        int v = (t >= off) ? s[t - off] : 0; __syncthreads();
        s[t] += v; __syncthreads();
    }
    g_part[t] = s[t];
}
__global__ __launch_bounds__(256) void scan3_kernel(){
    int b = blockIdx.x, i = b * 256 + threadIdx.x;
    g_row[i] = g_ex[i] + (b > 0 ? g_part[b - 1] : 0);
}
__global__ __launch_bounds__(256) void scatter_kernel(
    const float* __restrict__ pos, const int* __restrict__ src,
    const int* __restrict__ dst)
{
    int e = blockIdx.x * 256 + threadIdx.x;         // exact
    int sv = src[e], dv = dst[e];
    float dx = pos[3*dv]   - pos[3*sv];
    float dy = pos[3*dv+1] - pos[3*sv+1];
    float dz = pos[3*dv+2] - pos[3*sv+2];
    float d = sqrtf(dx*dx + dy*dy + dz*dz);         // < sqrt(3) < DMAX
    int p = atomicAdd(&g_row[dv], 1);               // g_row[v] ends at end-offset
    g_ssrc[p] = sv;
    g_sx[p]   = d * ((float)(NT - 1) / DMAX);
}

// ---------------- per-layer filter table: T[i] = W(d_i) * C(d_i) ------------
__global__ __launch_bounds__(128) void table_kernel(
    const float* __restrict__ w1g, const float* __restrict__ b1g,
    const float* __restrict__ w2g, const float* __restrict__ b2g)
{
    int l = blockIdx.x >> 11, pt = blockIdx.x & (NT - 1);
    int n = threadIdx.x;
    float d = pt * (DMAX / (float)(NT - 1));
    __shared__ float ea[64];
    __shared__ float tm[128];
    if (n < 50){
        float srel = d * 0.2f;
        float env = expf(1.0f - 1.0f / (1.0f - srel * srel));
        const float step = 5.0f / 49.0f;
        float dd = d - step * (float)n;
        ea[n] = expf((-0.5f / (step * step)) * dd * dd) * env;
    }
    __syncthreads();
    float acc = b1g[l * 128 + n];
    #pragma unroll 10
    for (int k = 0; k < 50; k++)
        acc = fmaf(ea[k], w1g[(l * 50 + k) * 128 + n], acc);
    tm[n] = sspf(acc);
    __syncthreads();
    float acc2 = b2g[l * 128 + n];
    #pragma unroll 8
    for (int k = 0; k < 128; k++)
        acc2 = fmaf(tm[k], w2g[(l * 128 + k) * 128 + n], acc2);
    float C = 0.5f * (cosf(d * 0.62831853071795864769f) + 1.0f);
    g_table[(l * NT + pt) * 128 + n] = acc2 * C;
}

// ---------------- weight prep: bf16 transpose of 9 node matrices ------------
__global__ __launch_bounds__(256) void wprep_kernel(
    const float* __restrict__ c1, const float* __restrict__ c2,
    const float* __restrict__ lw)
{
    int gid = blockIdx.x * 256 + threadIdx.x;       // 576*256 = 147456 exact
    int mat = gid >> 14, r = gid & 16383;
    int n = r & 127, k = r >> 7;
    int l = mat / 3, w = mat % 3;
    const float* base = (w == 0 ? c1 : w == 1 ? c2 : lw) + (size_t)l * HID * HID;
    g_wT[(size_t)mat * HID * HID + n * 128 + k] = f2bfbits(base[k * 128 + n]);
}

// ---------------- layer-0 conv1: emb gather + h init + GEMM -----------------
// weights streamed from L2; LDS = 8.2 KB -> high occupancy
__global__ __launch_bounds__(256) void conv1_kernel(
    const int* __restrict__ z, const float* __restrict__ emb)
{
    __shared__ __align__(16) unsigned short a_s[32 * 128];    // 8 KB
    __shared__ int zl[32];
    int tid = threadIdx.x;
    int wave = tid >> 6, lane = tid & 63, quad = lane >> 4, l16 = lane & 15;
    int mtile = (wave & 1) * 16, nbase = (wave >> 1) * 64;
    for (int t = blockIdx.x; t < NTILES; t += gridDim.x){
        int base = t * 32;
        __syncthreads();
        if (tid < 32) zl[tid] = (base + tid < N_NODES) ? z[base + tid] : 0;
        __syncthreads();
        for (int i = tid; i < 512; i += 256){
            int nn = i >> 4, c = i & 15, node = base + nn;
            int phys = c ^ (nn & 15);
            uint4 q = {0u, 0u, 0u, 0u};
            if (node < N_NODES){
                const float* p = &emb[(size_t)zl[nn] * 128 + c * 8];
                float4 f0 = *(const float4*)p;
                float4 f1 = *(const float4*)(p + 4);
                *(float4*)&g_h[(size_t)node * 128 + c * 8]     = f0;
                *(float4*)&g_h[(size_t)node * 128 + c * 8 + 4] = f1;
                q.x = (unsigned int)f2bfbits(f0.x) | ((unsigned int)f2bfbits(f0.y) << 16);
                q.y = (unsigned int)f2bfbits(f0.z) | ((unsigned int)f2bfbits(f0.w) << 16);
                q.z = (unsigned int)f2bfbits(f1.x) | ((unsigned int)f2bfbits(f1.y) << 16);
                q.w = (unsigned int)f2bfbits(f1.z) | ((unsigned int)f2bfbits(f1.w) << 16);
            }
            *(uint4*)&a_s[nn * 128 + phys * 8] = q;
        }
        __syncthreads();
        bf16x8 av[4];
        int arow = mtile + l16;
        #pragma unroll
        for (int ks = 0; ks < 4; ks++){
            int phys = (ks * 4 + quad) ^ (arow & 15);
            av[ks] = *(const bf16x8*)&a_s[arow * 128 + phys * 8];
        }
        f32x4 acc[4] = {};
        #pragma unroll
        for (int nt = 0; nt < 4; nt++){
            int n = nbase + nt * 16 + l16;
            #pragma unroll
            for (int ks = 0; ks < 4; ks++){
                bf16x8 bv = *(const bf16x8*)&g_wT[n * 128 + ks * 32 + quad * 8];
                acc[nt] = __builtin_amdgcn_mfma_f32_16x16x32_bf16(av[ks], bv, acc[nt], 0, 0, 0);
            }
        }
        #pragma unroll
        for (int nt = 0; nt < 4; nt++){
            int n = nbase + nt * 16 + l16;
            #pragma unroll
            for (int r = 0; r < 4; r++){
                int node = base + mtile + quad * 4 + r;
                if (node < N_NODES)
                    g_xfb[(size_t)node * 128 + n] = f2bfbits(acc[nt][r]);
            }
        }
    }
}

// ---------------- fused per-layer GEMM chain (weights streamed from L2) -----
// t = ssp(aggb@c2 + b2); h += t@lw + lb; if(!skip3) xfb = bf16(h)@c1next
// LDS = 17 KB (a_s reused for hb tile) -> ~5 blocks/CU (VGPR-limited)
__global__ __launch_bounds__(256) void fused_kernel(
    int l, const float* __restrict__ bias2, const float* __restrict__ biasl,
    int skip3)
{
    __shared__ __align__(16) unsigned short a_s[32 * 128];    // aggb tile / hb tile
    __shared__ __align__(16) unsigned short t_s[32 * 128];    // t tile
    __shared__ __align__(16) float s_b2[128];
    __shared__ __align__(16) float s_bl[128];
    int tid = threadIdx.x;
    const unsigned short* c2  = g_wT + (size_t)(l * 3 + 1) * HID * HID;
    const unsigned short* lw  = g_wT + (size_t)(l * 3 + 2) * HID * HID;
    const unsigned short* c1n = g_wT + (size_t)((l + 1) * 3) * HID * HID;
    if (tid < 128){ s_b2[tid] = bias2[tid]; s_bl[tid] = biasl[tid]; }

    int wave = tid >> 6, lane = tid & 63, quad = lane >> 4, l16 = lane & 15;
    int mtile = (wave & 1) * 16, nbase = (wave >> 1) * 64;

    for (int t = blockIdx.x; t < NTILES; t += gridDim.x){
        int base = t * 32;
        __syncthreads();                             // a_s free; s_b ready (iter 0)
        for (int i = tid; i < 512; i += 256){        // stage aggb tile
            int nn = i >> 4, c = i & 15, node = base + nn;
            int phys = c ^ (nn & 15);
            uint4 q = {0u, 0u, 0u, 0u};
            if (node < N_NODES)
                q = *(const uint4*)&g_aggb[(size_t)node * 128 + c * 8];
            *(uint4*)&a_s[nn * 128 + phys * 8] = q;
        }
        __syncthreads();

        // ---- GEMM1: acc = aggb @ c2   (c2 streamed from L2)
        int arow = mtile + l16;
        bf16x8 av[4];
        #pragma unroll
        for (int ks = 0; ks < 4; ks++){
            int phys = (ks * 4 + quad) ^ (arow & 15);
            av[ks] = *(const bf16x8*)&a_s[arow * 128 + phys * 8];
        }
        f32x4 acc[4] = {};
        #pragma unroll
        for (int nt = 0; nt < 4; nt++){
            int n = nbase + nt * 16 + l16;
            #pragma unroll
            for (int ks = 0; ks < 4; ks++){
                bf16x8 bv = *(const bf16x8*)&c2[n * 128 + ks * 32 + quad * 8];
                acc[nt] = __builtin_amdgcn_mfma_f32_16x16x32_bf16(av[ks], bv, acc[nt], 0, 0, 0);
            }
        }
        // epilogue1: t = ssp(acc + b2) -> t_s (swizzled scalar stores)
        #pragma unroll
        for (int nt = 0; nt < 4; nt++){
            int n = nbase + nt * 16 + l16;
            float bb = s_b2[n];
            int cch = n >> 3, jj = n & 7;
            #pragma unroll
            for (int r = 0; r < 4; r++){
                int row = mtile + quad * 4 + r;
                t_s[row * 128 + ((cch ^ (row & 15)) << 3) + jj] =
                    f2bfbits(sspf(acc[nt][r] + bb));
            }
        }
        __syncthreads();

        // ---- GEMM2: acc2 = t @ lw  (lw streamed from L2)
        #pragma unroll
        for (int ks = 0; ks < 4; ks++){
            int phys = (ks * 4 + quad) ^ (arow & 15);
            av[ks] = *(const bf16x8*)&t_s[arow * 128 + phys * 8];
        }
        f32x4 acc2[4] = {};
        #pragma unroll
        for (int nt = 0; nt < 4; nt++){
            int n = nbase + nt * 16 + l16;
            #pragma unroll
            for (int ks = 0; ks < 4; ks++){
                bf16x8 bv = *(const bf16x8*)&lw[n * 128 + ks * 32 + quad * 8];
                acc2[nt] = __builtin_amdgcn_mfma_f32_16x16x32_bf16(av[ks], bv, acc2[nt], 0, 0, 0);
            }
        }
        // epilogue2: h += acc2 + lb; stash bf16(h) into a_s for GEMM3
        #pragma unroll
        for (int nt = 0; nt < 4; nt++){
            int n = nbase + nt * 16 + l16;
            float bb = s_bl[n];
            int cch = n >> 3, jj = n & 7;
            #pragma unroll
            for (int r = 0; r < 4; r++){
                int row = mtile + quad * 4 + r;
                int node = base + row;
                if (node >= N_NODES) continue;
                size_t o = (size_t)node * 128 + n;
                float hv = g_h[o] + acc2[nt][r] + bb;
                g_h[o] = hv;
                if (!skip3)
                    a_s[row * 128 + ((cch ^ (row & 15)) << 3) + jj] = f2bfbits(hv);
            }
        }
        if (skip3) continue;
        __syncthreads();

        // ---- GEMM3: xfb = bf16(h) @ c1next  (c1next streamed from L2)
        #pragma unroll
        for (int ks = 0; ks < 4; ks++){
            int phys = (ks * 4 + quad) ^ (arow & 15);
            av[ks] = *(const bf16x8*)&a_s[arow * 128 + phys * 8];
        }
        f32x4 acc3[4] = {};
        #pragma unroll
        for (int nt = 0; nt < 4; nt++){
            int n = nbase + nt * 16 + l16;
            #pragma unroll
            for (int ks = 0; ks < 4; ks++){
                bf16x8 bv = *(const bf16x8*)&c1n[n * 128 + ks * 32 + quad * 8];
                acc3[nt] = __builtin_amdgcn_mfma_f32_16x16x32_bf16(av[ks], bv, acc3[nt], 0, 0, 0);
            }
        }
        #pragma unroll
        for (int nt = 0; nt < 4; nt++){
            int n = nbase + nt * 16 + l16;
            #pragma unroll
            for (int r = 0; r < 4; r++){
                int node = base + mtile + quad * 4 + r;
                if (node < N_NODES)
                    g_xfb[(size_t)node * 128 + n] = f2bfbits(acc3[nt][r]);
            }
        }
    }
}

// ---------------- CSR edge aggregation v3: 32 thr/node x 4 ch/thr -----------
__global__ __launch_bounds__(256) void agg_kernel(int l){
    const float* __restrict__ T = g_table + (size_t)l * NT * 128;
    int tid = threadIdx.x;
    int grp = tid >> 5, n0 = (tid & 31) * 4;
    int v = blockIdx.x * 8 + grp;                   // 6250 blocks * 8 = 50000 exact
    int e1 = g_row[v];
    int e0 = e1 - g_cnt[v];
    float a0 = 0.f, a1 = 0.f, a2 = 0.f, a3 = 0.f;
    int j = e0;
    for (; j + 2 <= e1; j += 2){
        int   sA = g_ssrc[j],  sB = g_ssrc[j+1];
        float xA = g_sx[j],    xB = g_sx[j+1];
        int iA = (int)xA, iB = (int)xB;
        float fA = xA - (float)iA, fB = xB - (float)iB;
        float4 tA0 = *(const float4*)&T[(size_t)iA * 128 + n0];
        float4 tA1 = *(const float4*)&T[(size_t)(iA + 1) * 128 + n0];
        float4 tB0 = *(const float4*)&T[(size_t)iB * 128 + n0];
        float4 tB1 = *(const float4*)&T[(size_t)(iB + 1) * 128 + n0];
        ushort4 gA = *(const ushort4*)&g_xfb[(size_t)sA * 128 + n0];
        ushort4 gB = *(const ushort4*)&g_xfb[(size_t)sB * 128 + n0];
        a0 = fmaf(fmaf(fA, tA1.x - tA0.x, tA0.x), bf2f(gA.x), a0);
        a1 = fmaf(fmaf(fA, tA1.y - tA0.y, tA0.y), bf2f(gA.y), a1);
        a2 = fmaf(fmaf(fA, tA1.z - tA0.z, tA0.z), bf2f(gA.z), a2);
        a3 = fmaf(fmaf(fA, tA1.w - tA0.w, tA0.w), bf2f(gA.w), a3);
        a0 = fmaf(fmaf(fB, tB1.x - tB0.x, tB0.x), bf2f(gB.x), a0);
        a1 = fmaf(fmaf(fB, tB1.y - tB0.y, tB0.y), bf2f(gB.y), a1);
        a2 = fmaf(fmaf(fB, tB1.z - tB0.z, tB0.z), bf2f(gB.z), a2);
        a3 = fmaf(fmaf(fB, tB1.w - tB0.w, tB0.w), bf2f(gB.w), a3);
    }
    if (j < e1){
        int s = g_ssrc[j]; float x = g_sx[j];
        int i0 = (int)x; float fr = x - (float)i0;
        float4 t0 = *(const float4*)&T[(size_t)i0 * 128 + n0];
        float4 t1 = *(const float4*)&T[(size_t)(i0 + 1) * 128 + n0];
        ushort4 g = *(const ushort4*)&g_xfb[(size_t)s * 128 + n0];
        a0 = fmaf(fmaf(fr, t1.x - t0.x, t0.x), bf2f(g.x), a0);
        a1 = fmaf(fmaf(fr, t1.y - t0.y, t0.y), bf2f(g.y), a1);
        a2 = fmaf(fmaf(fr, t1.z - t0.z, t0.z), bf2f(g.z), a2);
        a3 = fmaf(fmaf(fr, t1.w - t0.w, t0.w), bf2f(g.w), a3);
    }
    ushort4 o;
    o.x = f2bfbits(a0); o.y = f2bfbits(a1); o.z = f2bfbits(a2); o.w = f2bfbits(a3);
    *(ushort4*)&g_aggb[(size_t)v * 128 + n0] = o;
}

// ---------------- output head: per-node energy (no atomics) -----------------
__global__ __launch_bounds__(256) void head_kernel(
    const float* __restrict__ w1g, const float* __restrict__ b1g,
    const float* __restrict__ w2g, const float* __restrict__ b2g)
{
    __shared__ __align__(16) float w1h[128 * 64];   // 32 KB
    __shared__ __align__(16) float w2h[64];
    __shared__ __align__(16) float b1h[64];
    __shared__ __align__(16) float hrow[4][128];
    int tid = threadIdx.x;
    for (int i = tid; i < 128 * 64 / 4; i += 256)
        *(float4*)&w1h[i * 4] = *(const float4*)&w1g[i * 4];
    if (tid < 64){ w2h[tid] = w2g[tid]; b1h[tid] = b1g[tid]; }
    float sb2 = b2g[0];
    __syncthreads();
    int wave = tid >> 6, lane = tid & 63;
    for (int nb = blockIdx.x * 4; nb < N_NODES; nb += gridDim.x * 4){
        int node = nb + wave;
        __syncthreads();
        if (node < N_NODES){
            hrow[wave][lane]      = g_h[(size_t)node * 128 + lane];
            hrow[wave][64 + lane] = g_h[(size_t)node * 128 + 64 + lane];
        }
        __syncthreads();
        if (node < N_NODES){
            float acc = b1h[lane];
            #pragma unroll 8
            for (int k = 0; k < 128; k++)
                acc = fmaf(hrow[wave][k], w1h[k * 64 + lane], acc);
            acc = sspf(acc) * w2h[lane];
            #pragma unroll
            for (int off = 32; off > 0; off >>= 1) acc += __shfl_down(acc, off, 64);
            if (lane == 0) g_sx[node] = acc + sb2;   // reuse g_sx as e_atom
        }
    }
}

// ---------------- segment-sum of e_atom with LDS pre-reduction --------------
__global__ __launch_bounds__(256) void reduce_kernel(const int* __restrict__ batch){
    __shared__ float part[NGRAPHS];
    int tid = threadIdx.x;
    if (tid < NGRAPHS) part[tid] = 0.0f;
    __syncthreads();
    int i = blockIdx.x * 256 + tid;                 // 196 blocks
    if (i < N_NODES) atomicAdd(&part[batch[i]], g_sx[i]);
    __syncthreads();
    if (tid < NGRAPHS && part[tid] != 0.0f)
        __hip_atomic_fetch_add(&g_gout[tid], part[tid],
                               __ATOMIC_RELAXED, __HIP_MEMORY_SCOPE_AGENT);
}

__global__ void store_kernel(float* __restrict__ out){
    int i = threadIdx.x;
    if (i < NGRAPHS) out[i] = g_gout[i];
}

extern "C" void kernel_launch(void* const* d_in, const int* in_sizes, int n_in,
                              void* d_out, int out_size, void* d_ws, size_t ws_size,
                              hipStream_t stream)
{
    const int* z       = (const int*)d_in[0];
    const float* pos   = (const float*)d_in[1];
    const int* ei      = (const int*)d_in[2];
    const int* src = ei;
    const int* dst = ei + N_EDGES;
    const int* batch   = (const int*)d_in[3];
    const float* emb     = (const float*)d_in[4];
    const float* mlp_w1  = (const float*)d_in[5];
    const float* mlp_b1  = (const float*)d_in[6];
    const float* mlp_w2  = (const float*)d_in[7];
    const float* mlp_b2  = (const float*)d_in[8];
    const float* conv1_w = (const float*)d_in[9];
    const float* conv2_w = (const float*)d_in[10];
    const float* conv2_b = (const float*)d_in[11];
    const float* lin_w   = (const float*)d_in[12];
    const float* lin_b   = (const float*)d_in[13];
    const float* out1_w  = (const float*)d_in[14];
    const float* out1_b  = (const float*)d_in[15];
    const float* out2_w  = (const float*)d_in[16];
    const float* out2_b  = (const float*)d_in[17];
    (void)d_ws; (void)ws_size; (void)in_sizes; (void)n_in; (void)out_size;

    // --- one-time: CSR sort, tables, weight prep ---
    zero_cnt_kernel<<<196, 256, 0, stream>>>();
    hist_kernel<<<2500, 256, 0, stream>>>(dst);
    scan1_kernel<<<196, 256, 0, stream>>>();
    scan2_kernel<<<1, 256, 0, stream>>>();
    scan3_kernel<<<196, 256, 0, stream>>>();
    scatter_kernel<<<2500, 256, 0, stream>>>(pos, src, dst);
    table_kernel<<<NL * NT, 128, 0, stream>>>(mlp_w1, mlp_b1, mlp_w2, mlp_b2);
    wprep_kernel<<<576, 256, 0, stream>>>(conv1_w, conv2_w, lin_w);

    conv1_kernel<<<NTILES, 256, 0, stream>>>(z, emb);  // h init + layer-0 conv1
    for (int l = 0; l < NL; l++){
        agg_kernel<<<6250, 256, 0, stream>>>(l);
        fused_kernel<<<NTILES, 256, 0, stream>>>(l, conv2_b + (size_t)l * HID,
                                                 lin_b + (size_t)l * HID, l == NL - 1);
    }

    head_kernel<<<512, 256, 0, stream>>>(out1_w, out1_b, out2_w, out2_b);
    reduce_kernel<<<196, 256, 0, stream>>>(batch);
    store_kernel<<<1, 64, 0, stream>>>((float*)d_out);
}